// Round 12
// baseline (647.449 us; speedup 1.0000x reference)
//
#include <hip/hip_runtime.h>
#include <hip/hip_bf16.h>
#include <hip/hip_fp16.h>
#include <cstdio>

#define N_NODES 10000
#define M_NODEP 10240            // 80*128
#define N_EDGES 50000
#define M_EDGEP 50176            // 392*128
#define E_AUG   60000
#define E_AUGP  60160            // 470*128
#define ED      16
#define BI_OUT  272
#define KP      288              // 272 padded to 9*32

typedef __attribute__((ext_vector_type(8))) short s16x8;   // 8 bf16 (4 VGPRs)
typedef __attribute__((ext_vector_type(4))) short s16x4;
typedef __attribute__((ext_vector_type(8))) _Float16 h16x8;
typedef __attribute__((ext_vector_type(4))) _Float16 h16x4;
typedef __attribute__((ext_vector_type(4))) float f32x4;

__device__ inline void stc(float* p, float v){ *p = v; }
__device__ inline void stc(__hip_bfloat16* p, float v){ *p = __float2bfloat16(v); }
__device__ inline void stc(__half* p, float v){ *p = __float2half(v); }
__device__ inline float bf2f(short s){ return __uint_as_float(((unsigned)(unsigned short)s) << 16); }
__device__ inline short f2bf(float f){ __hip_bfloat16 h = __float2bfloat16(f); return *(short*)&h; }

// async global->LDS, 16 B per lane; LDS dest is wave-uniform base (lane*16 implicit)
__device__ __forceinline__ void gl2lds16(const void* g, void* l){
  __builtin_amdgcn_global_load_lds((const __attribute__((address_space(1))) void*)g,
                                   (__attribute__((address_space(3))) void*)l, 16, 0, 0);
}

// B pre-swizzle index: logical B^T element (row n, col k) of a matrix with
// kSteps = K/32  ->  element offset ((nb*kSteps + s)*8 + f)*512 + lane*8 + ii
// where nb=n>>7, f=(n>>4)&7, r=n&15, s=k>>5, q=(k>>3)&3, ii=k&7, lane=q*16+r.
__device__ inline size_t preidx(int n, int k, int kSteps){
  int nb = n >> 7, f = (n >> 4) & 7, r = n & 15;
  int s = k >> 5, q = (k >> 3) & 3, ii = k & 7;
  return ((((size_t)nb*kSteps + s)*8 + f)*64 + q*16 + r)*8 + ii;
}

// ---------- mean edge_attr per dst (self-loop fill) ----------
__global__ void edge_attr_sum_k(const float* __restrict__ ea, const int* __restrict__ ei,
                                float* __restrict__ meanat, float* __restrict__ cntF){
  int t = blockIdx.x*256 + threadIdx.x;
  if (t >= N_EDGES*ED) return;
  int e = t >> 4, j = t & 15;
  int dst = ei[N_EDGES + e];
  atomicAdd(&meanat[dst*ED + j], ea[t]);
  if (j == 0) atomicAdd(&cntF[dst], 1.0f);
}

__global__ void mean_div_k(float* __restrict__ meanat, const float* __restrict__ cntF){
  int t = blockIdx.x*256 + threadIdx.x;
  if (t >= N_NODES*ED) return;
  meanat[t] /= fmaxf(cntF[t>>4], 1.0f);
}

// ---------- CSR build ----------
__global__ void scan_k(const float* __restrict__ cntF, int* __restrict__ rowptr){
  __shared__ int s[1024];
  int tid = threadIdx.x;
  int loc[10]; int sum = 0;
  #pragma unroll
  for (int k = 0; k < 10; ++k){
    int i = tid*10 + k;
    int v = (i < N_NODES) ? ((int)cntF[i] + 1) : 0;   // +1 self loop
    loc[k] = sum; sum += v;
  }
  s[tid] = sum; __syncthreads();
  for (int off = 1; off < 1024; off <<= 1){
    int t2 = (tid >= off) ? s[tid-off] : 0;
    __syncthreads();
    s[tid] += t2;
    __syncthreads();
  }
  int pre = s[tid] - sum;
  #pragma unroll
  for (int k = 0; k < 10; ++k){
    int i = tid*10 + k;
    if (i < N_NODES) rowptr[i] = pre + loc[k];
  }
  if (tid == 1023) rowptr[N_NODES] = s[1023];
}

__global__ void scatter_k(const int* __restrict__ ei, const int* __restrict__ rowptr,
                          int* __restrict__ fill, int* __restrict__ csr){
  int e = blockIdx.x*256 + threadIdx.x;
  if (e >= E_AUG) return;
  int dst = (e < N_EDGES) ? ei[N_EDGES+e] : (e - N_EDGES);
  int pos = rowptr[dst] + atomicAdd(&fill[dst], 1);
  csr[pos] = e;
}

// ---------- MFMA bf16 GEMM, 128x128 tile, BK=64 (2 substeps per barrier) ----------
// A: LDS double-buffer of 128x64 tiles (two swizzled 128x32 substep panels each),
// one __syncthreads per 64-k iter; XOR-quad swizzle per substep (r7-verified):
// LDS elem (row,quad) = row*32 + ((quad+(row>>1))&3)*8.
// B: fragment-order layout (preidx), 4 x 1KB coalesced loads per 32-k step,
// prefetched one step ahead in registers.
template<typename TC, bool BIAS, bool RELU>
__global__ __launch_bounds__(256)
void mfma_gemm_k(const __hip_bfloat16* __restrict__ A, const __hip_bfloat16* __restrict__ Bp,
                 TC* __restrict__ C, const float* __restrict__ bias,
                 int Mstore, int K, int lda, int ldc){
  __shared__ __align__(16) __hip_bfloat16 Asm[2][8192];
  const int tid = threadIdx.x;
  const int lane = tid & 63, wave = tid >> 6;
  const int wm = (wave >> 1) * 64, wn = (wave & 1) * 64;
  const int m0 = blockIdx.x * 128, n0 = blockIdx.y * 128;
  const int quad = lane >> 4, r16 = lane & 15;
  const int S = K >> 5;                          // 32-k steps

  f32x4 acc[4][4];
  #pragma unroll
  for (int i = 0; i < 4; ++i)
    #pragma unroll
    for (int j = 0; j < 4; ++j)
      acc[i][j] = (f32x4){0.f, 0.f, 0.f, 0.f};

  const int rl = lane >> 2, cq = lane & 3;
  const int row0 = wave*32 + rl;
  const int qg = (cq - ((row0 >> 1) & 3)) & 3;
  const __hip_bfloat16* ga0 = &A[(size_t)(m0 + row0)*lda + qg*8];
  const __hip_bfloat16* ga1 = &A[(size_t)(m0 + row0 + 16)*lda + qg*8];
  const int aoff0 = (wave*32)*32, aoff1 = (wave*32 + 16)*32;

  const __hip_bfloat16* gB = Bp + (((size_t)blockIdx.y*S)*8 + (wn >> 4))*512 + (size_t)lane*8;

  // stage 32-k step t into LDS buffer buf, substep panel (t&1)
  auto stage = [&](int t, int buf){
    int k0 = t*32;
    __hip_bfloat16* base = &Asm[buf][(t & 1)*4096];
    gl2lds16(ga0 + k0, base + aoff0);
    gl2lds16(ga1 + k0, base + aoff1);
  };

  // prologue: stage steps 0 (+1) into buffer 0, load B step 0
  stage(0, 0);
  if (S > 1) stage(1, 0);
  s16x8 bcur[4], bnxt[4];
  #pragma unroll
  for (int j = 0; j < 4; ++j) bcur[j] = *(const s16x8*)(gB + j*512);

  for (int s = 0; s < S; ++s){
    if ((s & 1) == 0){
      __syncthreads();                           // one barrier per 64-k
      int nb = ((s >> 1) + 1) & 1;
      if (s + 2 < S) stage(s + 2, nb);
      if (s + 3 < S) stage(s + 3, nb);
    }
    if (s + 1 < S){
      const __hip_bfloat16* gBn = gB + (size_t)(s+1)*4096;
      #pragma unroll
      for (int j = 0; j < 4; ++j) bnxt[j] = *(const s16x8*)(gBn + j*512);
    }
    const __hip_bfloat16* base = &Asm[(s >> 1) & 1][(s & 1)*4096];
    s16x8 af[4];
    #pragma unroll
    for (int i = 0; i < 4; ++i){
      int row = wm + i*16 + r16;
      af[i] = *(const s16x8*)&base[row*32 + (((quad + (row >> 1)) & 3) << 3)];
    }
    #pragma unroll
    for (int i = 0; i < 4; ++i)
      #pragma unroll
      for (int j = 0; j < 4; ++j)
        acc[i][j] = __builtin_amdgcn_mfma_f32_16x16x32_bf16(af[i], bcur[j], acc[i][j], 0, 0, 0);
    #pragma unroll
    for (int j = 0; j < 4; ++j) bcur[j] = bnxt[j];
  }
  #pragma unroll
  for (int i = 0; i < 4; ++i){
    #pragma unroll
    for (int reg = 0; reg < 4; ++reg){
      int gr = m0 + wm + i*16 + quad*4 + reg;
      if (gr >= Mstore) continue;
      #pragma unroll
      for (int j = 0; j < 4; ++j){
        int gc = n0 + wn + j*16 + r16;
        float v = acc[i][j][reg];
        if (BIAS) v += bias[gc];
        if (RELU) v = fmaxf(v, 0.f);
        stc(&C[(size_t)gr*ldc + gc], v);
      }
    }
  }
}

// ---------- fused weight prep (pre-swizzled B layouts) ----------
__global__ void prep_weights_k(
    const float* __restrict__ Wl0, const float* __restrict__ Wr0, const float* __restrict__ We0,
    const float* __restrict__ Wl1, const float* __restrict__ Wr1, const float* __restrict__ We1,
    const float* __restrict__ Wl2, const float* __restrict__ Wr2, const float* __restrict__ We2,
    const float* __restrict__ Wl3, const float* __restrict__ Wr3, const float* __restrict__ We3,
    const float* __restrict__ Wm1, const float* __restrict__ bm1,
    const float* __restrict__ Wm2, const float* __restrict__ bm2,
    __hip_bfloat16* __restrict__ WTa, __hip_bfloat16* __restrict__ WeTa,
    __hip_bfloat16* __restrict__ Wm1T, __hip_bfloat16* __restrict__ Wm2T,
    float* __restrict__ bm1p, float* __restrict__ bm2p){
  int t = blockIdx.x*256 + threadIdx.x;
  if (t < 16384){
    int half = t >> 13, r = t & 8191, i = r >> 8, j = r & 255;       // Wl0/Wr0 [32x256]
    WTa[preidx(half*256 + j, i, 1)] = __float2bfloat16(half ? Wr0[r] : Wl0[r]);
  } else if (t < 278528){
    int u = t - 16384, half = u >> 17, r = u & 131071, i = r >> 9, j = r & 511;
    WTa[16384 + preidx(half*512 + j, i, 8)] = __float2bfloat16(half ? Wr1[r] : Wl1[r]);
  } else if (t < 802816){
    int u = t - 278528, half = u >> 18, r = u & 262143, i = r >> 9, j = r & 511;
    WTa[278528 + preidx(half*512 + j, i, 16)] = __float2bfloat16(half ? Wr2[r] : Wl2[r]);
  } else if (t < 1327104){
    int u = t - 802816, half = u >> 18, r = u & 262143, i = r >> 9, j = r & 511;
    WTa[802816 + preidx(half*512 + j, i, 16)] = __float2bfloat16(half ? Wr3[r] : Wl3[r]);
  }
  if (t < 8192){
    int n = t >> 5, k = t & 31;
    WeTa[preidx(n, k, 1)] = __float2bfloat16((k < 16) ? We0[k*256 + n] : 0.f);
  } else if (t < 24576){
    int u = t - 8192, n = u >> 5, k = u & 31;
    WeTa[8192 + preidx(n, k, 1)] = __float2bfloat16((k < 16) ? We1[k*512 + n] : 0.f);
  } else if (t < 40960){
    int u = t - 24576, n = u >> 5, k = u & 31;
    WeTa[24576 + preidx(n, k, 1)] = __float2bfloat16((k < 16) ? We2[k*512 + n] : 0.f);
  } else if (t < 57344){
    int u = t - 40960, n = u >> 5, k = u & 31;
    WeTa[40960 + preidx(n, k, 1)] = __float2bfloat16((k < 16) ? We3[k*512 + n] : 0.f);
  }
  if (t < 384*KP){
    int n = t / KP, k = t - n*KP;
    Wm1T[preidx(n, k, 9)] = __float2bfloat16((n < BI_OUT && k < BI_OUT) ? Wm1[(size_t)k*BI_OUT + n] : 0.f);
  }
  if (t < 128*KP){
    int n = t / KP, k = t - n*KP;
    Wm2T[preidx(n, k, 9)] = __float2bfloat16((n < 32 && k < BI_OUT) ? Wm2[(size_t)k*32 + n] : 0.f);
  }
  if (t < 384) bm1p[t] = (t < BI_OUT) ? bm1[t] : 0.f;
  if (t < 128) bm2p[t] = (t < 32) ? bm2[t] : 0.f;
}

__global__ void cast_h_k(const float* __restrict__ h, __hip_bfloat16* __restrict__ hb, int K){
  int t = blockIdx.x*256 + threadIdx.x;
  if (t >= M_NODEP*K) return;
  int r = t / K;
  hb[t] = (r < N_NODES) ? __float2bfloat16(h[t]) : __float2bfloat16(0.f);
}

// ea_aug -> bf16 [E_AUGP x 32] (K padded 16->32)
__global__ void cast_ea_k(const float* __restrict__ ea, const float* __restrict__ meanat,
                          __hip_bfloat16* __restrict__ eab){
  int t = blockIdx.x*256 + threadIdx.x;
  if (t >= E_AUGP*32) return;
  int e = t >> 5, j = t & 31;
  float v = 0.f;
  if (j < 16){
    if (e < N_EDGES) v = ea[(size_t)e*ED + j];
    else if (e < E_AUG) v = meanat[(size_t)(e - N_EDGES)*ED + j];
  }
  eab[t] = __float2bfloat16(v);
}

// Wbi[k<272][i<1024][j<16] -> WtAll: 2 chunks, each rows [0,cw)=L, [cw,2cw)=R; col=i&511
__global__ void wbi_transpose_k(const float* __restrict__ Wbi, __hip_bfloat16* __restrict__ WtAll){
  int t = blockIdx.x*256 + threadIdx.x;
  if (t >= BI_OUT*1024*ED) return;
  int k = t >> 14, r = t & 16383;
  int i = r >> 4, j = r & 15;
  int c = (k < 136) ? 0 : 1;
  int kb = c*136;
  const int cw = 2176;                         // 136*16
  size_t baseE = (size_t)c * 2228224;          // 4352*512
  int row = ((i >= 512) ? cw : 0) + (k - kb)*16 + j;
  WtAll[baseE + preidx(row, i & 511, 16)] = __float2bfloat16(Wbi[t]);
}

// ---------- fused GAT: one-pass online softmax + aggregate, 1 wave per dst ----------
template<int DOUT, bool RELU>
__global__ __launch_bounds__(256)
void gat_fused_k(const __hip_bfloat16* __restrict__ XLXR, const __half* __restrict__ EE,
                 const int* __restrict__ ei, const int* __restrict__ rowptr,
                 const int* __restrict__ csr, const float* __restrict__ att,
                 const float* __restrict__ b, __hip_bfloat16* __restrict__ hb){
  constexpr int NI = DOUT/64;
  constexpr int W2 = 2*DOUT;
  int wave = threadIdx.x >> 6, lane = threadIdx.x & 63;
  int n = blockIdx.x*4 + wave;
  if (n >= N_NODES) return;
  int r0 = rowptr[n], r1 = rowptr[n+1];
  int pp = r0 + lane;
  int e_l = 0, s_l = 0;
  if (pp < r1){
    e_l = csr[pp];
    s_l = (e_l < N_EDGES) ? ei[e_l] : (e_l - N_EDGES);
  }
  float xr[NI], at[NI], acc[NI];
  #pragma unroll
  for (int i = 0; i < NI; ++i){
    int d = lane*NI + i;
    xr[i]  = bf2f(((const short*)XLXR)[(size_t)n*W2 + DOUT + d]);
    at[i]  = att[d];
    acc[i] = 0.f;
  }
  float mrun = -1e30f, den = 0.f;
  int p = r0;
  for (; p + 1 < r1; p += 2){
    int i0 = p - r0, i1 = i0 + 1;
    int e0, s0, e1, s1;
    if (i1 < 64){
      e0 = __shfl(e_l, i0, 64); s0 = __shfl(s_l, i0, 64);
      e1 = __shfl(e_l, i1, 64); s1 = __shfl(s_l, i1, 64);
    } else {
      if (i0 < 64){ e0 = __shfl(e_l, i0, 64); s0 = __shfl(s_l, i0, 64); }
      else { e0 = csr[p]; s0 = (e0 < N_EDGES) ? ei[e0] : (e0 - N_EDGES); }
      e1 = csr[p+1]; s1 = (e1 < N_EDGES) ? ei[e1] : (e1 - N_EDGES);
    }
    const short* xp0 = (const short*)XLXR + (size_t)s0*W2 + lane*NI;
    const short* xp1 = (const short*)XLXR + (size_t)s1*W2 + lane*NI;
    const _Float16* ep0 = (const _Float16*)EE + (size_t)e0*DOUT + lane*NI;
    const _Float16* ep1 = (const _Float16*)EE + (size_t)e1*DOUT + lane*NI;
    float xl0[NI], xl1[NI];
    float a0 = 0.f, a1 = 0.f;
    if constexpr (NI == 8){
      s16x8 xv0 = *(const s16x8*)xp0; h16x8 ev0 = *(const h16x8*)ep0;
      s16x8 xv1 = *(const s16x8*)xp1; h16x8 ev1 = *(const h16x8*)ep1;
      #pragma unroll
      for (int i = 0; i < 8; ++i){
        xl0[i] = bf2f(xv0[i]); xl1[i] = bf2f(xv1[i]);
        float v0 = xl0[i] + xr[i] + (float)ev0[i];
        float v1 = xl1[i] + xr[i] + (float)ev1[i];
        v0 = (v0 > 0.f) ? v0 : 0.2f*v0;
        v1 = (v1 > 0.f) ? v1 : 0.2f*v1;
        a0 += at[i]*v0; a1 += at[i]*v1;
      }
    } else {
      s16x4 xv0 = *(const s16x4*)xp0; h16x4 ev0 = *(const h16x4*)ep0;
      s16x4 xv1 = *(const s16x4*)xp1; h16x4 ev1 = *(const h16x4*)ep1;
      #pragma unroll
      for (int i = 0; i < 4; ++i){
        xl0[i] = bf2f(xv0[i]); xl1[i] = bf2f(xv1[i]);
        float v0 = xl0[i] + xr[i] + (float)ev0[i];
        float v1 = xl1[i] + xr[i] + (float)ev1[i];
        v0 = (v0 > 0.f) ? v0 : 0.2f*v0;
        v1 = (v1 > 0.f) ? v1 : 0.2f*v1;
        a0 += at[i]*v0; a1 += at[i]*v1;
      }
    }
    #pragma unroll
    for (int off = 32; off; off >>= 1){
      a0 += __shfl_xor(a0, off, 64);
      a1 += __shfl_xor(a1, off, 64);
    }
    float mnew = fmaxf(mrun, fmaxf(a0, a1));
    float s = __expf(mrun - mnew);
    float w0 = __expf(a0 - mnew);
    float w1 = __expf(a1 - mnew);
    den = den*s + w0 + w1;
    #pragma unroll
    for (int i = 0; i < NI; ++i) acc[i] = acc[i]*s + w0*xl0[i] + w1*xl1[i];
    mrun = mnew;
  }
  if (p < r1){
    int i0 = p - r0;
    int e0, s0;
    if (i0 < 64){ e0 = __shfl(e_l, i0, 64); s0 = __shfl(s_l, i0, 64); }
    else { e0 = csr[p]; s0 = (e0 < N_EDGES) ? ei[e0] : (e0 - N_EDGES); }
    const short* xp0 = (const short*)XLXR + (size_t)s0*W2 + lane*NI;
    const _Float16* ep0 = (const _Float16*)EE + (size_t)e0*DOUT + lane*NI;
    float xl0[NI];
    float a0 = 0.f;
    #pragma unroll
    for (int i = 0; i < NI; ++i){
      xl0[i] = bf2f(xp0[i]);
      float v0 = xl0[i] + xr[i] + (float)ep0[i];
      v0 = (v0 > 0.f) ? v0 : 0.2f*v0;
      a0 += at[i]*v0;
    }
    #pragma unroll
    for (int off = 32; off; off >>= 1) a0 += __shfl_xor(a0, off, 64);
    float mnew = fmaxf(mrun, a0);
    float s = __expf(mrun - mnew);
    float w0 = __expf(a0 - mnew);
    den = den*s + w0;
    #pragma unroll
    for (int i = 0; i < NI; ++i) acc[i] = acc[i]*s + w0*xl0[i];
    mrun = mnew;
  }
  float dinv = 1.0f / fmaxf(den, 1e-16f);
  if constexpr (NI == 8){
    s16x8 o;
    #pragma unroll
    for (int i = 0; i < 8; ++i){
      float v = b[lane*8 + i] + acc[i]*dinv;
      o[i] = f2bf(RELU ? fmaxf(v, 0.f) : v);
    }
    *(s16x8*)((short*)hb + (size_t)n*DOUT + lane*8) = o;
  } else {
    s16x4 o;
    #pragma unroll
    for (int i = 0; i < 4; ++i){
      float v = b[lane*4 + i] + acc[i]*dinv;
      o[i] = f2bf(RELU ? fmaxf(v, 0.f) : v);
    }
    *(s16x4*)((short*)hb + (size_t)n*DOUT + lane*4) = o;
  }
}

// ---------- per-edge bilinear, dst-ordered via CSR (PR rows L1/L2-hot) ----------
__global__ void bi_k(const __hip_bfloat16* __restrict__ P, const float* __restrict__ ea,
                     const int* __restrict__ ei, const int* __restrict__ csr,
                     const float* __restrict__ bbi, __hip_bfloat16* __restrict__ bi,
                     int kb, int kcnt){
  int cw = kcnt*ED, w2 = 2*cw;
  int g = blockIdx.x*256 + threadIdx.x;
  if (g >= E_AUG*kcnt) return;
  int p = g / kcnt, k = g - p*kcnt;
  int e = csr[p];
  if (e >= N_EDGES) return;                    // self-loop pseudo-edge: no bi output
  int src = ei[e], dst = ei[N_EDGES+e];
  const __hip_bfloat16* pl = P + (size_t)src*w2 + k*ED;
  const __hip_bfloat16* pr = P + (size_t)dst*w2 + cw + k*ED;
  const float* eap = ea + (size_t)e*ED;
  float s = 0.f;
  #pragma unroll
  for (int j = 0; j < ED; ++j)
    s += eap[j]*(__bfloat162float(pl[j]) + __bfloat162float(pr[j]));
  int kg = kb + k;
  bi[(size_t)e*KP + kg] = __float2bfloat16(s + bbi[kg]);
}

// ---------- final tiny GEMV + sigmoid ----------
__global__ void out_k(const __hip_bfloat16* __restrict__ m2, const float* __restrict__ Wm3,
                      const float* __restrict__ bm3, float* __restrict__ out){
  int n = blockIdx.x*256 + threadIdx.x;
  if (n >= N_EDGES) return;
  float acc = bm3[0];
  #pragma unroll
  for (int j = 0; j < 32; ++j) acc += __bfloat162float(m2[(size_t)n*128 + j])*Wm3[j];
  out[n] = 1.0f/(1.0f + __expf(-acc));
}

extern "C" void kernel_launch(void* const* d_in, const int* in_sizes, int n_in,
                              void* d_out, int out_size, void* d_ws, size_t ws_size,
                              hipStream_t stream) {
  const float* x   = (const float*)d_in[0];
  const float* ea  = (const float*)d_in[1];
  const int*   ei  = (const int*)d_in[2];
  const float* Wl[4]  = {(const float*)d_in[3],(const float*)d_in[8],(const float*)d_in[13],(const float*)d_in[18]};
  const float* Wr[4]  = {(const float*)d_in[4],(const float*)d_in[9],(const float*)d_in[14],(const float*)d_in[19]};
  const float* We[4]  = {(const float*)d_in[5],(const float*)d_in[10],(const float*)d_in[15],(const float*)d_in[20]};
  const float* att[4] = {(const float*)d_in[6],(const float*)d_in[11],(const float*)d_in[16],(const float*)d_in[21]};
  const float* bia[4] = {(const float*)d_in[7],(const float*)d_in[12],(const float*)d_in[17],(const float*)d_in[22]};
  const float* Wbi = (const float*)d_in[23];
  const float* bbi = (const float*)d_in[24];
  const float* Wm1 = (const float*)d_in[25];
  const float* bm1 = (const float*)d_in[26];
  const float* Wm2 = (const float*)d_in[27];
  const float* bm2 = (const float*)d_in[28];
  const float* Wm3 = (const float*)d_in[29];
  const float* bm3 = (const float*)d_in[30];
  float* out = (float*)d_out;

  char* ws = (char*)d_ws;
  size_t off = 0;
  auto alloc = [&](size_t b){ off = (off + 255) & ~(size_t)255; size_t o = off; off += b; return o; };
  size_t o_bi   = alloc((size_t)M_EDGEP*KP*2);           // 28.90 MB
  size_t o_XLXR = alloc((size_t)M_NODEP*1024*2);         // 20.97 MB
  size_t o_hb   = alloc((size_t)M_NODEP*512*2);          // 10.49 MB
  size_t o_eab  = alloc((size_t)E_AUGP*32*2);            // 3.85 MB
  size_t o_WTa  = alloc((size_t)1327104*2);              // 2.65 MB
  size_t o_WeTa = alloc((size_t)57344*2);
  size_t o_WtA  = alloc((size_t)8704*512*2);             // 8.91 MB
  size_t o_EEP  = alloc((size_t)90000000);               // EE (61.6) | P-chunk (89.1) | m1,m2
  size_t o_Wm1T = alloc((size_t)384*KP*2);
  size_t o_Wm2T = alloc((size_t)128*KP*2);
  size_t o_bm1p = alloc(384*4);
  size_t o_bm2p = alloc(128*4);
  size_t o_ma   = alloc((size_t)N_NODES*ED*4);
  size_t o_cnt  = alloc(40000);
  size_t o_rp   = alloc(40004);
  size_t o_fill = alloc(40000);
  size_t o_csr  = alloc(240000);
  if (off > ws_size){
    fprintf(stderr, "kernel_launch: workspace too small: need %zu have %zu\n", off, ws_size);
    return;
  }

  float* meanat = (float*)(ws + o_ma);
  float* cntF   = (float*)(ws + o_cnt);
  int*   rowptr = (int*)(ws + o_rp);
  int*   fill   = (int*)(ws + o_fill);
  int*   csr    = (int*)(ws + o_csr);
  __hip_bfloat16* XLXR = (__hip_bfloat16*)(ws + o_XLXR);
  __hip_bfloat16* hb   = (__hip_bfloat16*)(ws + o_hb);
  __hip_bfloat16* eab  = (__hip_bfloat16*)(ws + o_eab);
  __hip_bfloat16* WTa  = (__hip_bfloat16*)(ws + o_WTa);
  __hip_bfloat16* WeTa = (__hip_bfloat16*)(ws + o_WeTa);
  __hip_bfloat16* WtA  = (__hip_bfloat16*)(ws + o_WtA);
  __half*        EE    = (__half*)(ws + o_EEP);
  __hip_bfloat16* P    = (__hip_bfloat16*)(ws + o_EEP);
  __hip_bfloat16* Wm1T = (__hip_bfloat16*)(ws + o_Wm1T);
  __hip_bfloat16* Wm2T = (__hip_bfloat16*)(ws + o_Wm2T);
  float* bm1p = (float*)(ws + o_bm1p);
  float* bm2p = (float*)(ws + o_bm2p);
  __hip_bfloat16* bi = (__hip_bfloat16*)(ws + o_bi);
  __hip_bfloat16* m1 = (__hip_bfloat16*)(ws + o_EEP);
  __hip_bfloat16* m2 = (__hip_bfloat16*)(ws + o_EEP + 40000000);

  // mean_attr + CSR build
  hipMemsetAsync(ws + o_ma, 0, (o_cnt - o_ma) + 40000, stream);
  hipMemsetAsync(ws + o_fill, 0, 40000, stream);
  edge_attr_sum_k<<<3125, 256, 0, stream>>>(ea, ei, meanat, cntF);
  mean_div_k<<<625, 256, 0, stream>>>(meanat, cntF);
  scan_k<<<1, 1024, 0, stream>>>(cntF, rowptr);
  scatter_k<<<235, 256, 0, stream>>>(ei, rowptr, fill, csr);

  // casts + all weight prep upfront
  cast_h_k<<<(M_NODEP*32 + 255)/256, 256, 0, stream>>>(x, hb, 32);
  cast_ea_k<<<(E_AUGP*32 + 255)/256, 256, 0, stream>>>(ea, meanat, eab);
  prep_weights_k<<<5184, 256, 0, stream>>>(
      Wl[0], Wr[0], We[0], Wl[1], Wr[1], We[1], Wl[2], Wr[2], We[2], Wl[3], Wr[3], We[3],
      Wm1, bm1, Wm2, bm2, WTa, WeTa, Wm1T, Wm2T, bm1p, bm2p);
  wbi_transpose_k<<<(BI_OUT*1024*ED + 255)/256, 256, 0, stream>>>(Wbi, WtA);

  const int dins[4]  = {32, 256, 512, 512};
  const int douts[4] = {256, 512, 512, 512};
  const int wtOff[4] = {0, 16384, 278528, 802816};
  const int weOff[4] = {0, 8192, 24576, 40960};
  for (int L = 0; L < 4; ++L){
    int din = dins[L], dn = douts[L];
    dim3 g1(M_NODEP/128, 2*dn/128);
    mfma_gemm_k<__hip_bfloat16,false,false><<<g1, 256, 0, stream>>>(
        hb, WTa + wtOff[L], XLXR, nullptr, N_NODES, din, din, 2*dn);
    dim3 ge(E_AUGP/128, dn/128);
    mfma_gemm_k<__half,false,false><<<ge, 256, 0, stream>>>(
        eab, WeTa + weOff[L], EE, nullptr, E_AUG, 32, 32, dn);
    if (dn == 256)
      gat_fused_k<256,true><<<2500, 256, 0, stream>>>(XLXR, EE, ei, rowptr, csr, att[L], bia[L], hb);
    else if (L == 3)
      gat_fused_k<512,false><<<2500, 256, 0, stream>>>(XLXR, EE, ei, rowptr, csr, att[L], bia[L], hb);
    else
      gat_fused_k<512,true><<<2500, 256, 0, stream>>>(XLXR, EE, ei, rowptr, csr, att[L], bia[L], hb);
  }
  // hb holds final node embeddings [M_NODEP x 512] bf16

  // merged PL|PR GEMM per chunk (2 chunks of 136 k's): N = 4352, then bilinear
  const int kbs[2]      = {0, 136};
  const int kcnts[2]    = {136, 136};
  const size_t baseE[2] = {0, 2228224};        // chunk elem offsets in WtA (4352*512)
  for (int c = 0; c < 2; ++c){
    int cw = kcnts[c]*ED, w2 = 2*cw;           // 2176 / 4352
    dim3 gp(M_NODEP/128, w2/128);
    mfma_gemm_k<__hip_bfloat16,false,false><<<gp, 256, 0, stream>>>(
        hb, WtA + baseE[c], P, nullptr, N_NODES, 512, 512, w2);
    bi_k<<<(E_AUG*kcnts[c] + 255)/256, 256, 0, stream>>>(P, ea, ei, csr, bbi, bi, kbs[c], kcnts[c]);
  }

  dim3 gm1(M_EDGEP/128, 3);
  mfma_gemm_k<__hip_bfloat16,true,true><<<gm1, 256, 0, stream>>>(bi, Wm1T, m1, bm1p, M_EDGEP, KP, KP, 384);
  dim3 gm2(M_EDGEP/128, 1);
  mfma_gemm_k<__hip_bfloat16,true,true><<<gm2, 256, 0, stream>>>(m1, Wm2T, m2, bm2p, M_EDGEP, KP, 384, 128);
  out_k<<<(N_EDGES + 255)/256, 256, 0, stream>>>(m2, Wm3, bm3, out);
}

// Round 13
// 632.177 us; speedup vs baseline: 1.0242x; 1.0242x over previous
//
#include <hip/hip_runtime.h>
#include <hip/hip_bf16.h>
#include <hip/hip_fp16.h>
#include <cstdio>

#define N_NODES 10000
#define M_NODEP 10240            // 80*128
#define N_EDGES 50000
#define M_EDGEP 50176            // 392*128
#define E_AUG   60000
#define E_AUGP  60160            // 470*128
#define ED      16
#define BI_OUT  272
#define KP      288              // 272 padded to 9*32

typedef __attribute__((ext_vector_type(8))) short s16x8;   // 8 bf16 (4 VGPRs)
typedef __attribute__((ext_vector_type(4))) short s16x4;
typedef __attribute__((ext_vector_type(8))) _Float16 h16x8;
typedef __attribute__((ext_vector_type(4))) _Float16 h16x4;
typedef __attribute__((ext_vector_type(4))) float f32x4;

__device__ inline void stc(float* p, float v){ *p = v; }
__device__ inline void stc(__hip_bfloat16* p, float v){ *p = __float2bfloat16(v); }
__device__ inline void stc(__half* p, float v){ *p = __float2half(v); }
__device__ inline float bf2f(short s){ return __uint_as_float(((unsigned)(unsigned short)s) << 16); }
__device__ inline short f2bf(float f){ __hip_bfloat16 h = __float2bfloat16(f); return *(short*)&h; }

// async global->LDS, 16 B per lane; LDS dest is wave-uniform base (lane*16 implicit)
__device__ __forceinline__ void gl2lds16(const void* g, void* l){
  __builtin_amdgcn_global_load_lds((const __attribute__((address_space(1))) void*)g,
                                   (__attribute__((address_space(3))) void*)l, 16, 0, 0);
}

// B pre-swizzle index: logical B^T element (row n, col k) of a matrix with
// kSteps = K/32  ->  element offset ((nb*kSteps + s)*8 + f)*512 + lane*8 + ii
// where nb=n>>7, f=(n>>4)&7, r=n&15, s=k>>5, q=(k>>3)&3, ii=k&7, lane=q*16+r.
__device__ inline size_t preidx(int n, int k, int kSteps){
  int nb = n >> 7, f = (n >> 4) & 7, r = n & 15;
  int s = k >> 5, q = (k >> 3) & 3, ii = k & 7;
  return ((((size_t)nb*kSteps + s)*8 + f)*64 + q*16 + r)*8 + ii;
}

// ---------- mean edge_attr per dst (self-loop fill) ----------
__global__ void edge_attr_sum_k(const float* __restrict__ ea, const int* __restrict__ ei,
                                float* __restrict__ meanat, float* __restrict__ cntF){
  int t = blockIdx.x*256 + threadIdx.x;
  if (t >= N_EDGES*ED) return;
  int e = t >> 4, j = t & 15;
  int dst = ei[N_EDGES + e];
  atomicAdd(&meanat[dst*ED + j], ea[t]);
  if (j == 0) atomicAdd(&cntF[dst], 1.0f);
}

__global__ void mean_div_k(float* __restrict__ meanat, const float* __restrict__ cntF){
  int t = blockIdx.x*256 + threadIdx.x;
  if (t >= N_NODES*ED) return;
  meanat[t] /= fmaxf(cntF[t>>4], 1.0f);
}

// ---------- CSR build ----------
__global__ void scan_k(const float* __restrict__ cntF, int* __restrict__ rowptr){
  __shared__ int s[1024];
  int tid = threadIdx.x;
  int loc[10]; int sum = 0;
  #pragma unroll
  for (int k = 0; k < 10; ++k){
    int i = tid*10 + k;
    int v = (i < N_NODES) ? ((int)cntF[i] + 1) : 0;   // +1 self loop
    loc[k] = sum; sum += v;
  }
  s[tid] = sum; __syncthreads();
  for (int off = 1; off < 1024; off <<= 1){
    int t2 = (tid >= off) ? s[tid-off] : 0;
    __syncthreads();
    s[tid] += t2;
    __syncthreads();
  }
  int pre = s[tid] - sum;
  #pragma unroll
  for (int k = 0; k < 10; ++k){
    int i = tid*10 + k;
    if (i < N_NODES) rowptr[i] = pre + loc[k];
  }
  if (tid == 1023) rowptr[N_NODES] = s[1023];
}

__global__ void scatter_k(const int* __restrict__ ei, const int* __restrict__ rowptr,
                          int* __restrict__ fill, int* __restrict__ csr){
  int e = blockIdx.x*256 + threadIdx.x;
  if (e >= E_AUG) return;
  int dst = (e < N_EDGES) ? ei[N_EDGES+e] : (e - N_EDGES);
  int pos = rowptr[dst] + atomicAdd(&fill[dst], 1);
  csr[pos] = e;
}

// ---------- MFMA bf16 GEMM, 128x128 tile, B from pre-swizzled global ----------
// (round-11 verified: best measured 63.4 us on the P chunks; BK=64 variant was
//  neutral-negative — pipelining tweaks on this K-loop shape don't help.)
// A: LDS double-buffer, single barrier per 32-k iter; XOR-quad swizzle.
// B: fragment-order layout (preidx), 4 x 1KB coalesced loads per k-step,
// prefetched one step ahead in registers (no barrier dependency).
template<typename TC, bool BIAS, bool RELU>
__global__ __launch_bounds__(256)
void mfma_gemm_k(const __hip_bfloat16* __restrict__ A, const __hip_bfloat16* __restrict__ Bp,
                 TC* __restrict__ C, const float* __restrict__ bias,
                 int Mstore, int K, int lda, int ldc){
  __shared__ __align__(16) __hip_bfloat16 Asm[2][4096];
  const int tid = threadIdx.x;
  const int lane = tid & 63, wave = tid >> 6;
  const int wm = (wave >> 1) * 64, wn = (wave & 1) * 64;
  const int m0 = blockIdx.x * 128, n0 = blockIdx.y * 128;
  const int quad = lane >> 4, r16 = lane & 15;
  const int kSteps = K >> 5;

  f32x4 acc[4][4];
  #pragma unroll
  for (int i = 0; i < 4; ++i)
    #pragma unroll
    for (int j = 0; j < 4; ++j)
      acc[i][j] = (f32x4){0.f, 0.f, 0.f, 0.f};

  const int rl = lane >> 2, cq = lane & 3;
  const int row0 = wave*32 + rl;
  const int qg = (cq - ((row0 >> 1) & 3)) & 3;
  const __hip_bfloat16* ga0 = &A[(size_t)(m0 + row0)*lda + qg*8];
  const __hip_bfloat16* ga1 = &A[(size_t)(m0 + row0 + 16)*lda + qg*8];
  const int aoff0 = (wave*32)*32, aoff1 = (wave*32 + 16)*32;

  const __hip_bfloat16* gB = Bp + (((size_t)blockIdx.y*kSteps)*8 + (wn >> 4))*512 + (size_t)lane*8;

  gl2lds16(ga0, &Asm[0][aoff0]);
  gl2lds16(ga1, &Asm[0][aoff1]);
  s16x8 bcur[4], bnxt[4];
  #pragma unroll
  for (int j = 0; j < 4; ++j) bcur[j] = *(const s16x8*)(gB + j*512);

  for (int s = 0; s < kSteps; ++s){
    __syncthreads();
    if (s + 1 < kSteps){
      int k0 = (s + 1) * 32;
      gl2lds16(ga0 + k0, &Asm[(s+1)&1][aoff0]);
      gl2lds16(ga1 + k0, &Asm[(s+1)&1][aoff1]);
      const __hip_bfloat16* gBn = gB + (size_t)(s+1)*4096;
      #pragma unroll
      for (int j = 0; j < 4; ++j) bnxt[j] = *(const s16x8*)(gBn + j*512);
    }
    s16x8 af[4];
    #pragma unroll
    for (int i = 0; i < 4; ++i){
      int row = wm + i*16 + r16;
      af[i] = *(const s16x8*)&Asm[s & 1][row*32 + (((quad + (row >> 1)) & 3) << 3)];
    }
    #pragma unroll
    for (int i = 0; i < 4; ++i)
      #pragma unroll
      for (int j = 0; j < 4; ++j)
        acc[i][j] = __builtin_amdgcn_mfma_f32_16x16x32_bf16(af[i], bcur[j], acc[i][j], 0, 0, 0);
    #pragma unroll
    for (int j = 0; j < 4; ++j) bcur[j] = bnxt[j];
  }
  #pragma unroll
  for (int i = 0; i < 4; ++i){
    #pragma unroll
    for (int reg = 0; reg < 4; ++reg){
      int gr = m0 + wm + i*16 + quad*4 + reg;
      if (gr >= Mstore) continue;
      #pragma unroll
      for (int j = 0; j < 4; ++j){
        int gc = n0 + wn + j*16 + r16;
        float v = acc[i][j][reg];
        if (BIAS) v += bias[gc];
        if (RELU) v = fmaxf(v, 0.f);
        stc(&C[(size_t)gr*ldc + gc], v);
      }
    }
  }
}

// ---------- fused weight prep (pre-swizzled B layouts) ----------
__global__ void prep_weights_k(
    const float* __restrict__ Wl0, const float* __restrict__ Wr0, const float* __restrict__ We0,
    const float* __restrict__ Wl1, const float* __restrict__ Wr1, const float* __restrict__ We1,
    const float* __restrict__ Wl2, const float* __restrict__ Wr2, const float* __restrict__ We2,
    const float* __restrict__ Wl3, const float* __restrict__ Wr3, const float* __restrict__ We3,
    const float* __restrict__ Wm1, const float* __restrict__ bm1,
    const float* __restrict__ Wm2, const float* __restrict__ bm2,
    __hip_bfloat16* __restrict__ WTa, __hip_bfloat16* __restrict__ WeTa,
    __hip_bfloat16* __restrict__ Wm1T, __hip_bfloat16* __restrict__ Wm2T,
    float* __restrict__ bm1p, float* __restrict__ bm2p){
  int t = blockIdx.x*256 + threadIdx.x;
  if (t < 16384){
    int half = t >> 13, r = t & 8191, i = r >> 8, j = r & 255;       // Wl0/Wr0 [32x256]
    WTa[preidx(half*256 + j, i, 1)] = __float2bfloat16(half ? Wr0[r] : Wl0[r]);
  } else if (t < 278528){
    int u = t - 16384, half = u >> 17, r = u & 131071, i = r >> 9, j = r & 511;
    WTa[16384 + preidx(half*512 + j, i, 8)] = __float2bfloat16(half ? Wr1[r] : Wl1[r]);
  } else if (t < 802816){
    int u = t - 278528, half = u >> 18, r = u & 262143, i = r >> 9, j = r & 511;
    WTa[278528 + preidx(half*512 + j, i, 16)] = __float2bfloat16(half ? Wr2[r] : Wl2[r]);
  } else if (t < 1327104){
    int u = t - 802816, half = u >> 18, r = u & 262143, i = r >> 9, j = r & 511;
    WTa[802816 + preidx(half*512 + j, i, 16)] = __float2bfloat16(half ? Wr3[r] : Wl3[r]);
  }
  if (t < 8192){
    int n = t >> 5, k = t & 31;
    WeTa[preidx(n, k, 1)] = __float2bfloat16((k < 16) ? We0[k*256 + n] : 0.f);
  } else if (t < 24576){
    int u = t - 8192, n = u >> 5, k = u & 31;
    WeTa[8192 + preidx(n, k, 1)] = __float2bfloat16((k < 16) ? We1[k*512 + n] : 0.f);
  } else if (t < 40960){
    int u = t - 24576, n = u >> 5, k = u & 31;
    WeTa[24576 + preidx(n, k, 1)] = __float2bfloat16((k < 16) ? We2[k*512 + n] : 0.f);
  } else if (t < 57344){
    int u = t - 40960, n = u >> 5, k = u & 31;
    WeTa[40960 + preidx(n, k, 1)] = __float2bfloat16((k < 16) ? We3[k*512 + n] : 0.f);
  }
  if (t < 384*KP){
    int n = t / KP, k = t - n*KP;
    Wm1T[preidx(n, k, 9)] = __float2bfloat16((n < BI_OUT && k < BI_OUT) ? Wm1[(size_t)k*BI_OUT + n] : 0.f);
  }
  if (t < 128*KP){
    int n = t / KP, k = t - n*KP;
    Wm2T[preidx(n, k, 9)] = __float2bfloat16((n < 32 && k < BI_OUT) ? Wm2[(size_t)k*32 + n] : 0.f);
  }
  if (t < 384) bm1p[t] = (t < BI_OUT) ? bm1[t] : 0.f;
  if (t < 128) bm2p[t] = (t < 32) ? bm2[t] : 0.f;
}

__global__ void cast_h_k(const float* __restrict__ h, __hip_bfloat16* __restrict__ hb, int K){
  int t = blockIdx.x*256 + threadIdx.x;
  if (t >= M_NODEP*K) return;
  int r = t / K;
  hb[t] = (r < N_NODES) ? __float2bfloat16(h[t]) : __float2bfloat16(0.f);
}

// ea_aug -> bf16 [E_AUGP x 32] (K padded 16->32)
__global__ void cast_ea_k(const float* __restrict__ ea, const float* __restrict__ meanat,
                          __hip_bfloat16* __restrict__ eab){
  int t = blockIdx.x*256 + threadIdx.x;
  if (t >= E_AUGP*32) return;
  int e = t >> 5, j = t & 31;
  float v = 0.f;
  if (j < 16){
    if (e < N_EDGES) v = ea[(size_t)e*ED + j];
    else if (e < E_AUG) v = meanat[(size_t)(e - N_EDGES)*ED + j];
  }
  eab[t] = __float2bfloat16(v);
}

// Wbi[k<272][i<1024][j<16] -> WtAll: 2 chunks, each rows [0,cw)=L, [cw,2cw)=R; col=i&511
__global__ void wbi_transpose_k(const float* __restrict__ Wbi, __hip_bfloat16* __restrict__ WtAll){
  int t = blockIdx.x*256 + threadIdx.x;
  if (t >= BI_OUT*1024*ED) return;
  int k = t >> 14, r = t & 16383;
  int i = r >> 4, j = r & 15;
  int c = (k < 136) ? 0 : 1;
  int kb = c*136;
  const int cw = 2176;                         // 136*16
  size_t baseE = (size_t)c * 2228224;          // 4352*512
  int row = ((i >= 512) ? cw : 0) + (k - kb)*16 + j;
  WtAll[baseE + preidx(row, i & 511, 16)] = __float2bfloat16(Wbi[t]);
}

// ---------- fused GAT: one-pass online softmax + aggregate, 1 wave per dst ----------
// d-indexing lane-blocked: d = lane*NI + i; 4-edge unrolled main loop
// (4 independent butterfly chains + one rescale per 4 edges).
template<int DOUT, bool RELU>
__global__ __launch_bounds__(256)
void gat_fused_k(const __hip_bfloat16* __restrict__ XLXR, const __half* __restrict__ EE,
                 const int* __restrict__ ei, const int* __restrict__ rowptr,
                 const int* __restrict__ csr, const float* __restrict__ att,
                 const float* __restrict__ b, __hip_bfloat16* __restrict__ hb){
  constexpr int NI = DOUT/64;
  constexpr int W2 = 2*DOUT;
  int wave = threadIdx.x >> 6, lane = threadIdx.x & 63;
  int n = blockIdx.x*4 + wave;
  if (n >= N_NODES) return;
  int r0 = rowptr[n], r1 = rowptr[n+1];
  int pp = r0 + lane;
  int e_l = 0, s_l = 0;
  if (pp < r1){
    e_l = csr[pp];
    s_l = (e_l < N_EDGES) ? ei[e_l] : (e_l - N_EDGES);
  }
  float xr[NI], at[NI], acc[NI];
  #pragma unroll
  for (int i = 0; i < NI; ++i){
    int d = lane*NI + i;
    xr[i]  = bf2f(((const short*)XLXR)[(size_t)n*W2 + DOUT + d]);
    at[i]  = att[d];
    acc[i] = 0.f;
  }
  // fetch edge/src for segment position p (idx = p-r0)
  auto getes = [&](int p, int &e, int &s){
    int idx = p - r0;
    if (idx < 64){ e = __shfl(e_l, idx, 64); s = __shfl(s_l, idx, 64); }
    else { e = csr[p]; s = (e < N_EDGES) ? ei[e] : (e - N_EDGES); }
  };
  float mrun = -1e30f, den = 0.f;
  int p = r0;
  // ---- 4-edge unrolled ----
  for (; p + 3 < r1; p += 4){
    int ee4[4], ss4[4];
    #pragma unroll
    for (int u = 0; u < 4; ++u) getes(p + u, ee4[u], ss4[u]);
    float xl[4][NI], a[4];
    #pragma unroll
    for (int u = 0; u < 4; ++u){
      const short* xp = (const short*)XLXR + (size_t)ss4[u]*W2 + lane*NI;
      const _Float16* ep = (const _Float16*)EE + (size_t)ee4[u]*DOUT + lane*NI;
      float au = 0.f;
      if constexpr (NI == 8){
        s16x8 xv = *(const s16x8*)xp; h16x8 ev = *(const h16x8*)ep;
        #pragma unroll
        for (int i = 0; i < 8; ++i){
          xl[u][i] = bf2f(xv[i]);
          float v = xl[u][i] + xr[i] + (float)ev[i];
          v = (v > 0.f) ? v : 0.2f*v;
          au += at[i]*v;
        }
      } else {
        s16x4 xv = *(const s16x4*)xp; h16x4 ev = *(const h16x4*)ep;
        #pragma unroll
        for (int i = 0; i < 4; ++i){
          xl[u][i] = bf2f(xv[i]);
          float v = xl[u][i] + xr[i] + (float)ev[i];
          v = (v > 0.f) ? v : 0.2f*v;
          au += at[i]*v;
        }
      }
      a[u] = au;
    }
    #pragma unroll
    for (int off = 32; off; off >>= 1){
      #pragma unroll
      for (int u = 0; u < 4; ++u) a[u] += __shfl_xor(a[u], off, 64);
    }
    float mnew = fmaxf(mrun, fmaxf(fmaxf(a[0], a[1]), fmaxf(a[2], a[3])));
    float sc = __expf(mrun - mnew);
    float w0 = __expf(a[0] - mnew), w1 = __expf(a[1] - mnew);
    float w2 = __expf(a[2] - mnew), w3 = __expf(a[3] - mnew);
    den = den*sc + w0 + w1 + w2 + w3;
    #pragma unroll
    for (int i = 0; i < NI; ++i)
      acc[i] = acc[i]*sc + w0*xl[0][i] + w1*xl[1][i] + w2*xl[2][i] + w3*xl[3][i];
    mrun = mnew;
  }
  // ---- 2-edge step ----
  for (; p + 1 < r1; p += 2){
    int e0, s0, e1, s1;
    getes(p, e0, s0); getes(p + 1, e1, s1);
    const short* xp0 = (const short*)XLXR + (size_t)s0*W2 + lane*NI;
    const short* xp1 = (const short*)XLXR + (size_t)s1*W2 + lane*NI;
    const _Float16* ep0 = (const _Float16*)EE + (size_t)e0*DOUT + lane*NI;
    const _Float16* ep1 = (const _Float16*)EE + (size_t)e1*DOUT + lane*NI;
    float xl0[NI], xl1[NI];
    float a0 = 0.f, a1 = 0.f;
    #pragma unroll
    for (int i = 0; i < NI; ++i){
      xl0[i] = bf2f(xp0[i]); xl1[i] = bf2f(xp1[i]);
      float v0 = xl0[i] + xr[i] + (float)ep0[i];
      float v1 = xl1[i] + xr[i] + (float)ep1[i];
      v0 = (v0 > 0.f) ? v0 : 0.2f*v0;
      v1 = (v1 > 0.f) ? v1 : 0.2f*v1;
      a0 += at[i]*v0; a1 += at[i]*v1;
    }
    #pragma unroll
    for (int off = 32; off; off >>= 1){
      a0 += __shfl_xor(a0, off, 64);
      a1 += __shfl_xor(a1, off, 64);
    }
    float mnew = fmaxf(mrun, fmaxf(a0, a1));
    float sc = __expf(mrun - mnew);
    float w0 = __expf(a0 - mnew);
    float w1 = __expf(a1 - mnew);
    den = den*sc + w0 + w1;
    #pragma unroll
    for (int i = 0; i < NI; ++i) acc[i] = acc[i]*sc + w0*xl0[i] + w1*xl1[i];
    mrun = mnew;
  }
  // ---- 1-edge tail ----
  if (p < r1){
    int e0, s0;
    getes(p, e0, s0);
    const short* xp0 = (const short*)XLXR + (size_t)s0*W2 + lane*NI;
    const _Float16* ep0 = (const _Float16*)EE + (size_t)e0*DOUT + lane*NI;
    float xl0[NI];
    float a0 = 0.f;
    #pragma unroll
    for (int i = 0; i < NI; ++i){
      xl0[i] = bf2f(xp0[i]);
      float v0 = xl0[i] + xr[i] + (float)ep0[i];
      v0 = (v0 > 0.f) ? v0 : 0.2f*v0;
      a0 += at[i]*v0;
    }
    #pragma unroll
    for (int off = 32; off; off >>= 1) a0 += __shfl_xor(a0, off, 64);
    float mnew = fmaxf(mrun, a0);
    float sc = __expf(mrun - mnew);
    float w0 = __expf(a0 - mnew);
    den = den*sc + w0;
    #pragma unroll
    for (int i = 0; i < NI; ++i) acc[i] = acc[i]*sc + w0*xl0[i];
    mrun = mnew;
  }
  float dinv = 1.0f / fmaxf(den, 1e-16f);
  if constexpr (NI == 8){
    s16x8 o;
    #pragma unroll
    for (int i = 0; i < 8; ++i){
      float v = b[lane*8 + i] + acc[i]*dinv;
      o[i] = f2bf(RELU ? fmaxf(v, 0.f) : v);
    }
    *(s16x8*)((short*)hb + (size_t)n*DOUT + lane*8) = o;
  } else {
    s16x4 o;
    #pragma unroll
    for (int i = 0; i < 4; ++i){
      float v = b[lane*4 + i] + acc[i]*dinv;
      o[i] = f2bf(RELU ? fmaxf(v, 0.f) : v);
    }
    *(s16x4*)((short*)hb + (size_t)n*DOUT + lane*4) = o;
  }
}

// ---------- per-edge bilinear, dst-ordered via CSR (PR rows L1/L2-hot) ----------
__global__ void bi_k(const __hip_bfloat16* __restrict__ P, const float* __restrict__ ea,
                     const int* __restrict__ ei, const int* __restrict__ csr,
                     const float* __restrict__ bbi, __hip_bfloat16* __restrict__ bi,
                     int kb, int kcnt){
  int cw = kcnt*ED, w2 = 2*cw;
  int g = blockIdx.x*256 + threadIdx.x;
  if (g >= E_AUG*kcnt) return;
  int p = g / kcnt, k = g - p*kcnt;
  int e = csr[p];
  if (e >= N_EDGES) return;                    // self-loop pseudo-edge: no bi output
  int src = ei[e], dst = ei[N_EDGES+e];
  const __hip_bfloat16* pl = P + (size_t)src*w2 + k*ED;
  const __hip_bfloat16* pr = P + (size_t)dst*w2 + cw + k*ED;
  const float* eap = ea + (size_t)e*ED;
  float s = 0.f;
  #pragma unroll
  for (int j = 0; j < ED; ++j)
    s += eap[j]*(__bfloat162float(pl[j]) + __bfloat162float(pr[j]));
  int kg = kb + k;
  bi[(size_t)e*KP + kg] = __float2bfloat16(s + bbi[kg]);
}

// ---------- final tiny GEMV + sigmoid ----------
__global__ void out_k(const __hip_bfloat16* __restrict__ m2, const float* __restrict__ Wm3,
                      const float* __restrict__ bm3, float* __restrict__ out){
  int n = blockIdx.x*256 + threadIdx.x;
  if (n >= N_EDGES) return;
  float acc = bm3[0];
  #pragma unroll
  for (int j = 0; j < 32; ++j) acc += __bfloat162float(m2[(size_t)n*128 + j])*Wm3[j];
  out[n] = 1.0f/(1.0f + __expf(-acc));
}

extern "C" void kernel_launch(void* const* d_in, const int* in_sizes, int n_in,
                              void* d_out, int out_size, void* d_ws, size_t ws_size,
                              hipStream_t stream) {
  const float* x   = (const float*)d_in[0];
  const float* ea  = (const float*)d_in[1];
  const int*   ei  = (const int*)d_in[2];
  const float* Wl[4]  = {(const float*)d_in[3],(const float*)d_in[8],(const float*)d_in[13],(const float*)d_in[18]};
  const float* Wr[4]  = {(const float*)d_in[4],(const float*)d_in[9],(const float*)d_in[14],(const float*)d_in[19]};
  const float* We[4]  = {(const float*)d_in[5],(const float*)d_in[10],(const float*)d_in[15],(const float*)d_in[20]};
  const float* att[4] = {(const float*)d_in[6],(const float*)d_in[11],(const float*)d_in[16],(const float*)d_in[21]};
  const float* bia[4] = {(const float*)d_in[7],(const float*)d_in[12],(const float*)d_in[17],(const float*)d_in[22]};
  const float* Wbi = (const float*)d_in[23];
  const float* bbi = (const float*)d_in[24];
  const float* Wm1 = (const float*)d_in[25];
  const float* bm1 = (const float*)d_in[26];
  const float* Wm2 = (const float*)d_in[27];
  const float* bm2 = (const float*)d_in[28];
  const float* Wm3 = (const float*)d_in[29];
  const float* bm3 = (const float*)d_in[30];
  float* out = (float*)d_out;

  char* ws = (char*)d_ws;
  size_t off = 0;
  auto alloc = [&](size_t b){ off = (off + 255) & ~(size_t)255; size_t o = off; off += b; return o; };
  size_t o_bi   = alloc((size_t)M_EDGEP*KP*2);           // 28.90 MB
  size_t o_XLXR = alloc((size_t)M_NODEP*1024*2);         // 20.97 MB
  size_t o_hb   = alloc((size_t)M_NODEP*512*2);          // 10.49 MB
  size_t o_eab  = alloc((size_t)E_AUGP*32*2);            // 3.85 MB
  size_t o_WTa  = alloc((size_t)1327104*2);              // 2.65 MB
  size_t o_WeTa = alloc((size_t)57344*2);
  size_t o_WtA  = alloc((size_t)8704*512*2);             // 8.91 MB
  size_t o_EEP  = alloc((size_t)90000000);               // EE (61.6) | P-chunk (89.1) | m1,m2
  size_t o_Wm1T = alloc((size_t)384*KP*2);
  size_t o_Wm2T = alloc((size_t)128*KP*2);
  size_t o_bm1p = alloc(384*4);
  size_t o_bm2p = alloc(128*4);
  size_t o_ma   = alloc((size_t)N_NODES*ED*4);
  size_t o_cnt  = alloc(40000);
  size_t o_rp   = alloc(40004);
  size_t o_fill = alloc(40000);
  size_t o_csr  = alloc(240000);
  if (off > ws_size){
    fprintf(stderr, "kernel_launch: workspace too small: need %zu have %zu\n", off, ws_size);
    return;
  }

  float* meanat = (float*)(ws + o_ma);
  float* cntF   = (float*)(ws + o_cnt);
  int*   rowptr = (int*)(ws + o_rp);
  int*   fill   = (int*)(ws + o_fill);
  int*   csr    = (int*)(ws + o_csr);
  __hip_bfloat16* XLXR = (__hip_bfloat16*)(ws + o_XLXR);
  __hip_bfloat16* hb   = (__hip_bfloat16*)(ws + o_hb);
  __hip_bfloat16* eab  = (__hip_bfloat16*)(ws + o_eab);
  __hip_bfloat16* WTa  = (__hip_bfloat16*)(ws + o_WTa);
  __hip_bfloat16* WeTa = (__hip_bfloat16*)(ws + o_WeTa);
  __hip_bfloat16* WtA  = (__hip_bfloat16*)(ws + o_WtA);
  __half*        EE    = (__half*)(ws + o_EEP);
  __hip_bfloat16* P    = (__hip_bfloat16*)(ws + o_EEP);
  __hip_bfloat16* Wm1T = (__hip_bfloat16*)(ws + o_Wm1T);
  __hip_bfloat16* Wm2T = (__hip_bfloat16*)(ws + o_Wm2T);
  float* bm1p = (float*)(ws + o_bm1p);
  float* bm2p = (float*)(ws + o_bm2p);
  __hip_bfloat16* bi = (__hip_bfloat16*)(ws + o_bi);
  __hip_bfloat16* m1 = (__hip_bfloat16*)(ws + o_EEP);
  __hip_bfloat16* m2 = (__hip_bfloat16*)(ws + o_EEP + 40000000);

  // mean_attr + CSR build
  hipMemsetAsync(ws + o_ma, 0, (o_cnt - o_ma) + 40000, stream);
  hipMemsetAsync(ws + o_fill, 0, 40000, stream);
  edge_attr_sum_k<<<3125, 256, 0, stream>>>(ea, ei, meanat, cntF);
  mean_div_k<<<625, 256, 0, stream>>>(meanat, cntF);
  scan_k<<<1, 1024, 0, stream>>>(cntF, rowptr);
  scatter_k<<<235, 256, 0, stream>>>(ei, rowptr, fill, csr);

  // casts + all weight prep upfront
  cast_h_k<<<(M_NODEP*32 + 255)/256, 256, 0, stream>>>(x, hb, 32);
  cast_ea_k<<<(E_AUGP*32 + 255)/256, 256, 0, stream>>>(ea, meanat, eab);
  prep_weights_k<<<5184, 256, 0, stream>>>(
      Wl[0], Wr[0], We[0], Wl[1], Wr[1], We[1], Wl[2], Wr[2], We[2], Wl[3], Wr[3], We[3],
      Wm1, bm1, Wm2, bm2, WTa, WeTa, Wm1T, Wm2T, bm1p, bm2p);
  wbi_transpose_k<<<(BI_OUT*1024*ED + 255)/256, 256, 0, stream>>>(Wbi, WtA);

  const int dins[4]  = {32, 256, 512, 512};
  const int douts[4] = {256, 512, 512, 512};
  const int wtOff[4] = {0, 16384, 278528, 802816};
  const int weOff[4] = {0, 8192, 24576, 40960};
  for (int L = 0; L < 4; ++L){
    int din = dins[L], dn = douts[L];
    dim3 g1(M_NODEP/128, 2*dn/128);
    mfma_gemm_k<__hip_bfloat16,false,false><<<g1, 256, 0, stream>>>(
        hb, WTa + wtOff[L], XLXR, nullptr, N_NODES, din, din, 2*dn);
    dim3 ge(E_AUGP/128, dn/128);
    mfma_gemm_k<__half,false,false><<<ge, 256, 0, stream>>>(
        eab, WeTa + weOff[L], EE, nullptr, E_AUG, 32, 32, dn);
    if (dn == 256)
      gat_fused_k<256,true><<<2500, 256, 0, stream>>>(XLXR, EE, ei, rowptr, csr, att[L], bia[L], hb);
    else if (L == 3)
      gat_fused_k<512,false><<<2500, 256, 0, stream>>>(XLXR, EE, ei, rowptr, csr, att[L], bia[L], hb);
    else
      gat_fused_k<512,true><<<2500, 256, 0, stream>>>(XLXR, EE, ei, rowptr, csr, att[L], bia[L], hb);
  }
  // hb holds final node embeddings [M_NODEP x 512] bf16

  // merged PL|PR GEMM per chunk (2 chunks of 136 k's): N = 4352, then bilinear
  const int kbs[2]      = {0, 136};
  const int kcnts[2]    = {136, 136};
  const size_t baseE[2] = {0, 2228224};        // chunk elem offsets in WtA (4352*512)
  for (int c = 0; c < 2; ++c){
    int cw = kcnts[c]*ED, w2 = 2*cw;           // 2176 / 4352
    dim3 gp(M_NODEP/128, w2/128);
    mfma_gemm_k<__hip_bfloat16,false,false><<<gp, 256, 0, stream>>>(
        hb, WtA + baseE[c], P, nullptr, N_NODES, 512, 512, w2);
    bi_k<<<(E_AUG*kcnts[c] + 255)/256, 256, 0, stream>>>(P, ea, ei, csr, bbi, bi, kbs[c], kcnts[c]);
  }

  dim3 gm1(M_EDGEP/128, 3);
  mfma_gemm_k<__hip_bfloat16,true,true><<<gm1, 256, 0, stream>>>(bi, Wm1T, m1, bm1p, M_EDGEP, KP, KP, 384);
  dim3 gm2(M_EDGEP/128, 1);
  mfma_gemm_k<__hip_bfloat16,true,true><<<gm2, 256, 0, stream>>>(m1, Wm2T, m2, bm2p, M_EDGEP, KP, 384, 128);
  out_k<<<(N_EDGES + 255)/256, 256, 0, stream>>>(m2, Wm3, bm3, out);
}

// Round 14
// 609.774 us; speedup vs baseline: 1.0618x; 1.0367x over previous
//
#include <hip/hip_runtime.h>
#include <hip/hip_bf16.h>
#include <hip/hip_fp16.h>
#include <cstdio>

#define N_NODES 10000
#define M_NODEP 10240            // 80*128
#define N_EDGES 50000
#define M_EDGEP 50176            // 392*128
#define E_AUG   60000
#define E_AUGP  60160            // 470*128
#define ED      16
#define BI_OUT  272
#define KP      288              // 272 padded to 9*32

typedef __attribute__((ext_vector_type(8))) short s16x8;   // 8 bf16 (4 VGPRs)
typedef __attribute__((ext_vector_type(4))) short s16x4;
typedef __attribute__((ext_vector_type(8))) _Float16 h16x8;
typedef __attribute__((ext_vector_type(4))) _Float16 h16x4;
typedef __attribute__((ext_vector_type(4))) float f32x4;

__device__ inline void stc(float* p, float v){ *p = v; }
__device__ inline void stc(__hip_bfloat16* p, float v){ *p = __float2bfloat16(v); }
__device__ inline void stc(__half* p, float v){ *p = __float2half(v); }
__device__ inline float bf2f(short s){ return __uint_as_float(((unsigned)(unsigned short)s) << 16); }
__device__ inline short f2bf(float f){ __hip_bfloat16 h = __float2bfloat16(f); return *(short*)&h; }

// async global->LDS, 16 B per lane; LDS dest is wave-uniform base (lane*16 implicit)
__device__ __forceinline__ void gl2lds16(const void* g, void* l){
  __builtin_amdgcn_global_load_lds((const __attribute__((address_space(1))) void*)g,
                                   (__attribute__((address_space(3))) void*)l, 16, 0, 0);
}

// B pre-swizzle index: logical B^T element (row n, col k) of a matrix with
// kSteps = K/32  ->  element offset ((nb*kSteps + s)*8 + f)*512 + lane*8 + ii
// where nb=n>>7, f=(n>>4)&7, r=n&15, s=k>>5, q=(k>>3)&3, ii=k&7, lane=q*16+r.
__device__ inline size_t preidx(int n, int k, int kSteps){
  int nb = n >> 7, f = (n >> 4) & 7, r = n & 15;
  int s = k >> 5, q = (k >> 3) & 3, ii = k & 7;
  return ((((size_t)nb*kSteps + s)*8 + f)*64 + q*16 + r)*8 + ii;
}

// ---------- mean edge_attr per dst (self-loop fill) ----------
__global__ void edge_attr_sum_k(const float* __restrict__ ea, const int* __restrict__ ei,
                                float* __restrict__ meanat, float* __restrict__ cntF){
  int t = blockIdx.x*256 + threadIdx.x;
  if (t >= N_EDGES*ED) return;
  int e = t >> 4, j = t & 15;
  int dst = ei[N_EDGES + e];
  atomicAdd(&meanat[dst*ED + j], ea[t]);
  if (j == 0) atomicAdd(&cntF[dst], 1.0f);
}

__global__ void mean_div_k(float* __restrict__ meanat, const float* __restrict__ cntF){
  int t = blockIdx.x*256 + threadIdx.x;
  if (t >= N_NODES*ED) return;
  meanat[t] /= fmaxf(cntF[t>>4], 1.0f);
}

// ---------- CSR build ----------
__global__ void scan_k(const float* __restrict__ cntF, int* __restrict__ rowptr){
  __shared__ int s[1024];
  int tid = threadIdx.x;
  int loc[10]; int sum = 0;
  #pragma unroll
  for (int k = 0; k < 10; ++k){
    int i = tid*10 + k;
    int v = (i < N_NODES) ? ((int)cntF[i] + 1) : 0;   // +1 self loop
    loc[k] = sum; sum += v;
  }
  s[tid] = sum; __syncthreads();
  for (int off = 1; off < 1024; off <<= 1){
    int t2 = (tid >= off) ? s[tid-off] : 0;
    __syncthreads();
    s[tid] += t2;
    __syncthreads();
  }
  int pre = s[tid] - sum;
  #pragma unroll
  for (int k = 0; k < 10; ++k){
    int i = tid*10 + k;
    if (i < N_NODES) rowptr[i] = pre + loc[k];
  }
  if (tid == 1023) rowptr[N_NODES] = s[1023];
}

__global__ void scatter_k(const int* __restrict__ ei, const int* __restrict__ rowptr,
                          int* __restrict__ fill, int* __restrict__ csr){
  int e = blockIdx.x*256 + threadIdx.x;
  if (e >= E_AUG) return;
  int dst = (e < N_EDGES) ? ei[N_EDGES+e] : (e - N_EDGES);
  int pos = rowptr[dst] + atomicAdd(&fill[dst], 1);
  csr[pos] = e;
}

// ---------- MFMA bf16 GEMM, 128x128 tile, B from pre-swizzled global ----------
// (round-11 verified). A: LDS double-buffer, single barrier per 32-k iter;
// XOR-quad swizzle. B: fragment-order (preidx), prefetched one step ahead.
template<typename TC, bool BIAS, bool RELU>
__global__ __launch_bounds__(256)
void mfma_gemm_k(const __hip_bfloat16* __restrict__ A, const __hip_bfloat16* __restrict__ Bp,
                 TC* __restrict__ C, const float* __restrict__ bias,
                 int Mstore, int K, int lda, int ldc){
  __shared__ __align__(16) __hip_bfloat16 Asm[2][4096];
  const int tid = threadIdx.x;
  const int lane = tid & 63, wave = tid >> 6;
  const int wm = (wave >> 1) * 64, wn = (wave & 1) * 64;
  const int m0 = blockIdx.x * 128, n0 = blockIdx.y * 128;
  const int quad = lane >> 4, r16 = lane & 15;
  const int kSteps = K >> 5;

  f32x4 acc[4][4];
  #pragma unroll
  for (int i = 0; i < 4; ++i)
    #pragma unroll
    for (int j = 0; j < 4; ++j)
      acc[i][j] = (f32x4){0.f, 0.f, 0.f, 0.f};

  const int rl = lane >> 2, cq = lane & 3;
  const int row0 = wave*32 + rl;
  const int qg = (cq - ((row0 >> 1) & 3)) & 3;
  const __hip_bfloat16* ga0 = &A[(size_t)(m0 + row0)*lda + qg*8];
  const __hip_bfloat16* ga1 = &A[(size_t)(m0 + row0 + 16)*lda + qg*8];
  const int aoff0 = (wave*32)*32, aoff1 = (wave*32 + 16)*32;

  const __hip_bfloat16* gB = Bp + (((size_t)blockIdx.y*kSteps)*8 + (wn >> 4))*512 + (size_t)lane*8;

  gl2lds16(ga0, &Asm[0][aoff0]);
  gl2lds16(ga1, &Asm[0][aoff1]);
  s16x8 bcur[4], bnxt[4];
  #pragma unroll
  for (int j = 0; j < 4; ++j) bcur[j] = *(const s16x8*)(gB + j*512);

  for (int s = 0; s < kSteps; ++s){
    __syncthreads();
    if (s + 1 < kSteps){
      int k0 = (s + 1) * 32;
      gl2lds16(ga0 + k0, &Asm[(s+1)&1][aoff0]);
      gl2lds16(ga1 + k0, &Asm[(s+1)&1][aoff1]);
      const __hip_bfloat16* gBn = gB + (size_t)(s+1)*4096;
      #pragma unroll
      for (int j = 0; j < 4; ++j) bnxt[j] = *(const s16x8*)(gBn + j*512);
    }
    s16x8 af[4];
    #pragma unroll
    for (int i = 0; i < 4; ++i){
      int row = wm + i*16 + r16;
      af[i] = *(const s16x8*)&Asm[s & 1][row*32 + (((quad + (row >> 1)) & 3) << 3)];
    }
    #pragma unroll
    for (int i = 0; i < 4; ++i)
      #pragma unroll
      for (int j = 0; j < 4; ++j)
        acc[i][j] = __builtin_amdgcn_mfma_f32_16x16x32_bf16(af[i], bcur[j], acc[i][j], 0, 0, 0);
    #pragma unroll
    for (int j = 0; j < 4; ++j) bcur[j] = bnxt[j];
  }
  #pragma unroll
  for (int i = 0; i < 4; ++i){
    #pragma unroll
    for (int reg = 0; reg < 4; ++reg){
      int gr = m0 + wm + i*16 + quad*4 + reg;
      if (gr >= Mstore) continue;
      #pragma unroll
      for (int j = 0; j < 4; ++j){
        int gc = n0 + wn + j*16 + r16;
        float v = acc[i][j][reg];
        if (BIAS) v += bias[gc];
        if (RELU) v = fmaxf(v, 0.f);
        stc(&C[(size_t)gr*ldc + gc], v);
      }
    }
  }
}

// ---------- K=32 GEMM, multi-N-tile per block (A staged & frags loaded once) ----------
// For EE (M=E_AUGP) and layer-0 XLXR (M=M_NODEP). Bp layout: kSteps=1.
template<typename TC>
__global__ __launch_bounds__(256)
void gemm_k32_k(const __hip_bfloat16* __restrict__ A, const __hip_bfloat16* __restrict__ Bp,
                TC* __restrict__ C, int Mstore, int Ntiles, int lda, int ldc){
  __shared__ __align__(16) __hip_bfloat16 Asm[4096];
  const int tid = threadIdx.x;
  const int lane = tid & 63, wave = tid >> 6;
  const int wm = (wave >> 1) * 64, wn = (wave & 1) * 64;
  const int m0 = blockIdx.x * 128;
  const int quad = lane >> 4, r16 = lane & 15;

  const int rl = lane >> 2, cq = lane & 3;
  const int row0 = wave*32 + rl;
  const int qg = (cq - ((row0 >> 1) & 3)) & 3;
  gl2lds16(&A[(size_t)(m0 + row0)*lda + qg*8],      &Asm[(wave*32)*32]);
  gl2lds16(&A[(size_t)(m0 + row0 + 16)*lda + qg*8], &Asm[(wave*32 + 16)*32]);
  __syncthreads();
  s16x8 af[4];
  #pragma unroll
  for (int i = 0; i < 4; ++i){
    int row = wm + i*16 + r16;
    af[i] = *(const s16x8*)&Asm[row*32 + (((quad + (row >> 1)) & 3) << 3)];
  }

  const __hip_bfloat16* gB = Bp + (size_t)(wn >> 4)*512 + (size_t)lane*8;
  s16x8 bcur[4], bnxt[4];
  #pragma unroll
  for (int j = 0; j < 4; ++j) bcur[j] = *(const s16x8*)(gB + j*512);

  for (int nt = 0; nt < Ntiles; ++nt){
    if (nt + 1 < Ntiles){
      const __hip_bfloat16* gBn = gB + (size_t)(nt+1)*4096;
      #pragma unroll
      for (int j = 0; j < 4; ++j) bnxt[j] = *(const s16x8*)(gBn + j*512);
    }
    f32x4 acc[4][4];
    #pragma unroll
    for (int i = 0; i < 4; ++i)
      #pragma unroll
      for (int j = 0; j < 4; ++j)
        acc[i][j] = (f32x4){0.f, 0.f, 0.f, 0.f};
    #pragma unroll
    for (int i = 0; i < 4; ++i)
      #pragma unroll
      for (int j = 0; j < 4; ++j)
        acc[i][j] = __builtin_amdgcn_mfma_f32_16x16x32_bf16(af[i], bcur[j], acc[i][j], 0, 0, 0);
    int n0 = nt*128;
    #pragma unroll
    for (int i = 0; i < 4; ++i){
      #pragma unroll
      for (int reg = 0; reg < 4; ++reg){
        int gr = m0 + wm + i*16 + quad*4 + reg;
        if (gr >= Mstore) continue;
        #pragma unroll
        for (int j = 0; j < 4; ++j)
          stc(&C[(size_t)gr*ldc + n0 + wn + j*16 + r16], acc[i][j][reg]);
      }
    }
    #pragma unroll
    for (int j = 0; j < 4; ++j) bcur[j] = bnxt[j];
  }
}

// ---------- m2 GEMM with fused Wm3-dot + sigmoid epilogue ----------
// C-tile cols 0..31 are the valid m2 features; out[row] = sigmoid(relu(m2)·Wm3 + bm3)
__global__ __launch_bounds__(256)
void mlp2_out_k(const __hip_bfloat16* __restrict__ A, const __hip_bfloat16* __restrict__ Bp,
                const float* __restrict__ bias, const float* __restrict__ Wm3,
                const float* __restrict__ bm3, float* __restrict__ out,
                int Mstore, int K, int lda){
  __shared__ __align__(16) __hip_bfloat16 Asm[2][4096];
  const int tid = threadIdx.x;
  const int lane = tid & 63, wave = tid >> 6;
  const int wm = (wave >> 1) * 64, wn = (wave & 1) * 64;
  const int m0 = blockIdx.x * 128;
  const int quad = lane >> 4, r16 = lane & 15;
  const int kSteps = K >> 5;

  f32x4 acc[4][2];
  #pragma unroll
  for (int i = 0; i < 4; ++i)
    #pragma unroll
    for (int j = 0; j < 2; ++j)
      acc[i][j] = (f32x4){0.f, 0.f, 0.f, 0.f};

  const int rl = lane >> 2, cq = lane & 3;
  const int row0 = wave*32 + rl;
  const int qg = (cq - ((row0 >> 1) & 3)) & 3;
  const __hip_bfloat16* ga0 = &A[(size_t)(m0 + row0)*lda + qg*8];
  const __hip_bfloat16* ga1 = &A[(size_t)(m0 + row0 + 16)*lda + qg*8];
  const int aoff0 = (wave*32)*32, aoff1 = (wave*32 + 16)*32;

  // only frags for cols wn..wn+31 matter (cols >=32 are zero-padded weights)
  const __hip_bfloat16* gB = Bp + (size_t)(wn >> 4)*512 + (size_t)lane*8;

  gl2lds16(ga0, &Asm[0][aoff0]);
  gl2lds16(ga1, &Asm[0][aoff1]);
  s16x8 bcur[2], bnxt[2];
  #pragma unroll
  for (int j = 0; j < 2; ++j) bcur[j] = *(const s16x8*)(gB + j*512);

  for (int s = 0; s < kSteps; ++s){
    __syncthreads();
    if (s + 1 < kSteps){
      int k0 = (s + 1) * 32;
      gl2lds16(ga0 + k0, &Asm[(s+1)&1][aoff0]);
      gl2lds16(ga1 + k0, &Asm[(s+1)&1][aoff1]);
      const __hip_bfloat16* gBn = gB + (size_t)(s+1)*4096;
      #pragma unroll
      for (int j = 0; j < 2; ++j) bnxt[j] = *(const s16x8*)(gBn + j*512);
    }
    s16x8 af[4];
    #pragma unroll
    for (int i = 0; i < 4; ++i){
      int row = wm + i*16 + r16;
      af[i] = *(const s16x8*)&Asm[s & 1][row*32 + (((quad + (row >> 1)) & 3) << 3)];
    }
    #pragma unroll
    for (int i = 0; i < 4; ++i)
      #pragma unroll
      for (int j = 0; j < 2; ++j)
        acc[i][j] = __builtin_amdgcn_mfma_f32_16x16x32_bf16(af[i], bcur[j], acc[i][j], 0, 0, 0);
    #pragma unroll
    for (int j = 0; j < 2; ++j) bcur[j] = bnxt[j];
  }
  // fused epilogue: waves with wn==0 hold cols 0..31 in frags j=0,1
  if (wn == 0){
    float w3a = Wm3[r16], w3b = Wm3[16 + r16];
    float ba = bias[r16], bb = bias[16 + r16];
    #pragma unroll
    for (int i = 0; i < 4; ++i){
      #pragma unroll
      for (int reg = 0; reg < 4; ++reg){
        int gr = m0 + wm + i*16 + quad*4 + reg;
        float v0 = fmaxf(acc[i][0][reg] + ba, 0.f);
        float v1 = fmaxf(acc[i][1][reg] + bb, 0.f);
        float dot = v0*w3a + v1*w3b;
        #pragma unroll
        for (int off = 1; off < 16; off <<= 1) dot += __shfl_xor(dot, off, 64);
        if (r16 == 0 && gr < Mstore)
          out[gr] = 1.0f/(1.0f + __expf(-(dot + bm3[0])));
      }
    }
  }
}

// ---------- fused weight prep (pre-swizzled B layouts) ----------
__global__ void prep_weights_k(
    const float* __restrict__ Wl0, const float* __restrict__ Wr0, const float* __restrict__ We0,
    const float* __restrict__ Wl1, const float* __restrict__ Wr1, const float* __restrict__ We1,
    const float* __restrict__ Wl2, const float* __restrict__ Wr2, const float* __restrict__ We2,
    const float* __restrict__ Wl3, const float* __restrict__ Wr3, const float* __restrict__ We3,
    const float* __restrict__ Wm1, const float* __restrict__ bm1,
    const float* __restrict__ Wm2, const float* __restrict__ bm2,
    __hip_bfloat16* __restrict__ WTa, __hip_bfloat16* __restrict__ WeTa,
    __hip_bfloat16* __restrict__ Wm1T, __hip_bfloat16* __restrict__ Wm2T,
    float* __restrict__ bm1p, float* __restrict__ bm2p){
  int t = blockIdx.x*256 + threadIdx.x;
  if (t < 16384){
    int half = t >> 13, r = t & 8191, i = r >> 8, j = r & 255;       // Wl0/Wr0 [32x256]
    WTa[preidx(half*256 + j, i, 1)] = __float2bfloat16(half ? Wr0[r] : Wl0[r]);
  } else if (t < 278528){
    int u = t - 16384, half = u >> 17, r = u & 131071, i = r >> 9, j = r & 511;
    WTa[16384 + preidx(half*512 + j, i, 8)] = __float2bfloat16(half ? Wr1[r] : Wl1[r]);
  } else if (t < 802816){
    int u = t - 278528, half = u >> 18, r = u & 262143, i = r >> 9, j = r & 511;
    WTa[278528 + preidx(half*512 + j, i, 16)] = __float2bfloat16(half ? Wr2[r] : Wl2[r]);
  } else if (t < 1327104){
    int u = t - 802816, half = u >> 18, r = u & 262143, i = r >> 9, j = r & 511;
    WTa[802816 + preidx(half*512 + j, i, 16)] = __float2bfloat16(half ? Wr3[r] : Wl3[r]);
  }
  if (t < 8192){
    int n = t >> 5, k = t & 31;
    WeTa[preidx(n, k, 1)] = __float2bfloat16((k < 16) ? We0[k*256 + n] : 0.f);
  } else if (t < 24576){
    int u = t - 8192, n = u >> 5, k = u & 31;
    WeTa[8192 + preidx(n, k, 1)] = __float2bfloat16((k < 16) ? We1[k*512 + n] : 0.f);
  } else if (t < 40960){
    int u = t - 24576, n = u >> 5, k = u & 31;
    WeTa[24576 + preidx(n, k, 1)] = __float2bfloat16((k < 16) ? We2[k*512 + n] : 0.f);
  } else if (t < 57344){
    int u = t - 40960, n = u >> 5, k = u & 31;
    WeTa[40960 + preidx(n, k, 1)] = __float2bfloat16((k < 16) ? We3[k*512 + n] : 0.f);
  }
  if (t < 384*KP){
    int n = t / KP, k = t - n*KP;
    Wm1T[preidx(n, k, 9)] = __float2bfloat16((n < BI_OUT && k < BI_OUT) ? Wm1[(size_t)k*BI_OUT + n] : 0.f);
  }
  if (t < 128*KP){
    int n = t / KP, k = t - n*KP;
    Wm2T[preidx(n, k, 9)] = __float2bfloat16((n < 32 && k < BI_OUT) ? Wm2[(size_t)k*32 + n] : 0.f);
  }
  if (t < 384) bm1p[t] = (t < BI_OUT) ? bm1[t] : 0.f;
  if (t < 128) bm2p[t] = (t < 32) ? bm2[t] : 0.f;
}

__global__ void cast_h_k(const float* __restrict__ h, __hip_bfloat16* __restrict__ hb, int K){
  int t = blockIdx.x*256 + threadIdx.x;
  if (t >= M_NODEP*K) return;
  int r = t / K;
  hb[t] = (r < N_NODES) ? __float2bfloat16(h[t]) : __float2bfloat16(0.f);
}

// ea_aug -> bf16 [E_AUGP x 32] (K padded 16->32)
__global__ void cast_ea_k(const float* __restrict__ ea, const float* __restrict__ meanat,
                          __hip_bfloat16* __restrict__ eab){
  int t = blockIdx.x*256 + threadIdx.x;
  if (t >= E_AUGP*32) return;
  int e = t >> 5, j = t & 31;
  float v = 0.f;
  if (j < 16){
    if (e < N_EDGES) v = ea[(size_t)e*ED + j];
    else if (e < E_AUG) v = meanat[(size_t)(e - N_EDGES)*ED + j];
  }
  eab[t] = __float2bfloat16(v);
}

// Wbi[k<272][i<1024][j<16] -> WtAll: 2 chunks, each rows [0,cw)=L, [cw,2cw)=R; col=i&511
__global__ void wbi_transpose_k(const float* __restrict__ Wbi, __hip_bfloat16* __restrict__ WtAll){
  int t = blockIdx.x*256 + threadIdx.x;
  if (t >= BI_OUT*1024*ED) return;
  int k = t >> 14, r = t & 16383;
  int i = r >> 4, j = r & 15;
  int c = (k < 136) ? 0 : 1;
  int kb = c*136;
  const int cw = 2176;                         // 136*16
  size_t baseE = (size_t)c * 2228224;          // 4352*512
  int row = ((i >= 512) ? cw : 0) + (k - kb)*16 + j;
  WtAll[baseE + preidx(row, i & 511, 16)] = __float2bfloat16(Wbi[t]);
}

// ---------- fused GAT: one-pass online softmax + aggregate, 1 wave per dst ----------
template<int DOUT, bool RELU>
__global__ __launch_bounds__(256)
void gat_fused_k(const __hip_bfloat16* __restrict__ XLXR, const __half* __restrict__ EE,
                 const int* __restrict__ ei, const int* __restrict__ rowptr,
                 const int* __restrict__ csr, const float* __restrict__ att,
                 const float* __restrict__ b, __hip_bfloat16* __restrict__ hb){
  constexpr int NI = DOUT/64;
  constexpr int W2 = 2*DOUT;
  int wave = threadIdx.x >> 6, lane = threadIdx.x & 63;
  int n = blockIdx.x*4 + wave;
  if (n >= N_NODES) return;
  int r0 = rowptr[n], r1 = rowptr[n+1];
  int pp = r0 + lane;
  int e_l = 0, s_l = 0;
  if (pp < r1){
    e_l = csr[pp];
    s_l = (e_l < N_EDGES) ? ei[e_l] : (e_l - N_EDGES);
  }
  float xr[NI], at[NI], acc[NI];
  #pragma unroll
  for (int i = 0; i < NI; ++i){
    int d = lane*NI + i;
    xr[i]  = bf2f(((const short*)XLXR)[(size_t)n*W2 + DOUT + d]);
    at[i]  = att[d];
    acc[i] = 0.f;
  }
  auto getes = [&](int p, int &e, int &s){
    int idx = p - r0;
    if (idx < 64){ e = __shfl(e_l, idx, 64); s = __shfl(s_l, idx, 64); }
    else { e = csr[p]; s = (e < N_EDGES) ? ei[e] : (e - N_EDGES); }
  };
  float mrun = -1e30f, den = 0.f;
  int p = r0;
  for (; p + 3 < r1; p += 4){
    int ee4[4], ss4[4];
    #pragma unroll
    for (int u = 0; u < 4; ++u) getes(p + u, ee4[u], ss4[u]);
    float xl[4][NI], a[4];
    #pragma unroll
    for (int u = 0; u < 4; ++u){
      const short* xp = (const short*)XLXR + (size_t)ss4[u]*W2 + lane*NI;
      const _Float16* ep = (const _Float16*)EE + (size_t)ee4[u]*DOUT + lane*NI;
      float au = 0.f;
      if constexpr (NI == 8){
        s16x8 xv = *(const s16x8*)xp; h16x8 ev = *(const h16x8*)ep;
        #pragma unroll
        for (int i = 0; i < 8; ++i){
          xl[u][i] = bf2f(xv[i]);
          float v = xl[u][i] + xr[i] + (float)ev[i];
          v = (v > 0.f) ? v : 0.2f*v;
          au += at[i]*v;
        }
      } else {
        s16x4 xv = *(const s16x4*)xp; h16x4 ev = *(const h16x4*)ep;
        #pragma unroll
        for (int i = 0; i < 4; ++i){
          xl[u][i] = bf2f(xv[i]);
          float v = xl[u][i] + xr[i] + (float)ev[i];
          v = (v > 0.f) ? v : 0.2f*v;
          au += at[i]*v;
        }
      }
      a[u] = au;
    }
    #pragma unroll
    for (int off = 32; off; off >>= 1){
      #pragma unroll
      for (int u = 0; u < 4; ++u) a[u] += __shfl_xor(a[u], off, 64);
    }
    float mnew = fmaxf(mrun, fmaxf(fmaxf(a[0], a[1]), fmaxf(a[2], a[3])));
    float sc = __expf(mrun - mnew);
    float w0 = __expf(a[0] - mnew), w1 = __expf(a[1] - mnew);
    float w2 = __expf(a[2] - mnew), w3 = __expf(a[3] - mnew);
    den = den*sc + w0 + w1 + w2 + w3;
    #pragma unroll
    for (int i = 0; i < NI; ++i)
      acc[i] = acc[i]*sc + w0*xl[0][i] + w1*xl[1][i] + w2*xl[2][i] + w3*xl[3][i];
    mrun = mnew;
  }
  for (; p + 1 < r1; p += 2){
    int e0, s0, e1, s1;
    getes(p, e0, s0); getes(p + 1, e1, s1);
    const short* xp0 = (const short*)XLXR + (size_t)s0*W2 + lane*NI;
    const short* xp1 = (const short*)XLXR + (size_t)s1*W2 + lane*NI;
    const _Float16* ep0 = (const _Float16*)EE + (size_t)e0*DOUT + lane*NI;
    const _Float16* ep1 = (const _Float16*)EE + (size_t)e1*DOUT + lane*NI;
    float xl0[NI], xl1[NI];
    float a0 = 0.f, a1 = 0.f;
    #pragma unroll
    for (int i = 0; i < NI; ++i){
      xl0[i] = bf2f(xp0[i]); xl1[i] = bf2f(xp1[i]);
      float v0 = xl0[i] + xr[i] + (float)ep0[i];
      float v1 = xl1[i] + xr[i] + (float)ep1[i];
      v0 = (v0 > 0.f) ? v0 : 0.2f*v0;
      v1 = (v1 > 0.f) ? v1 : 0.2f*v1;
      a0 += at[i]*v0; a1 += at[i]*v1;
    }
    #pragma unroll
    for (int off = 32; off; off >>= 1){
      a0 += __shfl_xor(a0, off, 64);
      a1 += __shfl_xor(a1, off, 64);
    }
    float mnew = fmaxf(mrun, fmaxf(a0, a1));
    float sc = __expf(mrun - mnew);
    float w0 = __expf(a0 - mnew);
    float w1 = __expf(a1 - mnew);
    den = den*sc + w0 + w1;
    #pragma unroll
    for (int i = 0; i < NI; ++i) acc[i] = acc[i]*sc + w0*xl0[i] + w1*xl1[i];
    mrun = mnew;
  }
  if (p < r1){
    int e0, s0;
    getes(p, e0, s0);
    const short* xp0 = (const short*)XLXR + (size_t)s0*W2 + lane*NI;
    const _Float16* ep0 = (const _Float16*)EE + (size_t)e0*DOUT + lane*NI;
    float xl0[NI];
    float a0 = 0.f;
    #pragma unroll
    for (int i = 0; i < NI; ++i){
      xl0[i] = bf2f(xp0[i]);
      float v0 = xl0[i] + xr[i] + (float)ep0[i];
      v0 = (v0 > 0.f) ? v0 : 0.2f*v0;
      a0 += at[i]*v0;
    }
    #pragma unroll
    for (int off = 32; off; off >>= 1) a0 += __shfl_xor(a0, off, 64);
    float mnew = fmaxf(mrun, a0);
    float sc = __expf(mrun - mnew);
    float w0 = __expf(a0 - mnew);
    den = den*sc + w0;
    #pragma unroll
    for (int i = 0; i < NI; ++i) acc[i] = acc[i]*sc + w0*xl0[i];
    mrun = mnew;
  }
  float dinv = 1.0f / fmaxf(den, 1e-16f);
  if constexpr (NI == 8){
    s16x8 o;
    #pragma unroll
    for (int i = 0; i < 8; ++i){
      float v = b[lane*8 + i] + acc[i]*dinv;
      o[i] = f2bf(RELU ? fmaxf(v, 0.f) : v);
    }
    *(s16x8*)((short*)hb + (size_t)n*DOUT + lane*8) = o;
  } else {
    s16x4 o;
    #pragma unroll
    for (int i = 0; i < 4; ++i){
      float v = b[lane*4 + i] + acc[i]*dinv;
      o[i] = f2bf(RELU ? fmaxf(v, 0.f) : v);
    }
    *(s16x4*)((short*)hb + (size_t)n*DOUT + lane*4) = o;
  }
}

// ---------- per-edge bilinear, dst-ordered via CSR; 2 adjacent k per thread ----------
__global__ void bi_k(const __hip_bfloat16* __restrict__ P, const float* __restrict__ ea,
                     const int* __restrict__ ei, const int* __restrict__ csr,
                     const float* __restrict__ bbi, __hip_bfloat16* __restrict__ bi,
                     int kb){
  const int KH = 68;                           // 136/2 pairs
  const int cw = 2176, w2 = 4352;
  int g = blockIdx.x*256 + threadIdx.x;
  if (g >= E_AUG*KH) return;
  int p = g / KH, kp = g - p*KH;
  int k = kp*2;
  int e = csr[p];
  if (e >= N_EDGES) return;                    // self-loop pseudo-edge: no bi output
  int src = ei[e], dst = ei[N_EDGES+e];
  const s16x8* pl = (const s16x8*)(P + (size_t)src*w2 + k*ED);
  const s16x8* pr = (const s16x8*)(P + (size_t)dst*w2 + cw + k*ED);
  s16x8 pl0 = pl[0], pl1 = pl[1], pl2 = pl[2], pl3 = pl[3];
  s16x8 pr0 = pr[0], pr1 = pr[1], pr2 = pr[2], pr3 = pr[3];
  const float* eap = ea + (size_t)e*ED;
  float s0 = 0.f, s1 = 0.f;
  #pragma unroll
  for (int j = 0; j < 8; ++j){
    s0 += eap[j]  *(bf2f(pl0[j]) + bf2f(pr0[j]));
    s0 += eap[j+8]*(bf2f(pl1[j]) + bf2f(pr1[j]));
    s1 += eap[j]  *(bf2f(pl2[j]) + bf2f(pr2[j]));
    s1 += eap[j+8]*(bf2f(pl3[j]) + bf2f(pr3[j]));
  }
  int kg = kb + k;
  short2 o;
  o.x = f2bf(s0 + bbi[kg]);
  o.y = f2bf(s1 + bbi[kg+1]);
  *(short2*)((short*)bi + (size_t)e*KP + kg) = o;
}

extern "C" void kernel_launch(void* const* d_in, const int* in_sizes, int n_in,
                              void* d_out, int out_size, void* d_ws, size_t ws_size,
                              hipStream_t stream) {
  const float* x   = (const float*)d_in[0];
  const float* ea  = (const float*)d_in[1];
  const int*   ei  = (const int*)d_in[2];
  const float* Wl[4]  = {(const float*)d_in[3],(const float*)d_in[8],(const float*)d_in[13],(const float*)d_in[18]};
  const float* Wr[4]  = {(const float*)d_in[4],(const float*)d_in[9],(const float*)d_in[14],(const float*)d_in[19]};
  const float* We[4]  = {(const float*)d_in[5],(const float*)d_in[10],(const float*)d_in[15],(const float*)d_in[20]};
  const float* att[4] = {(const float*)d_in[6],(const float*)d_in[11],(const float*)d_in[16],(const float*)d_in[21]};
  const float* bia[4] = {(const float*)d_in[7],(const float*)d_in[12],(const float*)d_in[17],(const float*)d_in[22]};
  const float* Wbi = (const float*)d_in[23];
  const float* bbi = (const float*)d_in[24];
  const float* Wm1 = (const float*)d_in[25];
  const float* bm1 = (const float*)d_in[26];
  const float* Wm2 = (const float*)d_in[27];
  const float* bm2 = (const float*)d_in[28];
  const float* Wm3 = (const float*)d_in[29];
  const float* bm3 = (const float*)d_in[30];
  float* out = (float*)d_out;

  char* ws = (char*)d_ws;
  size_t off = 0;
  auto alloc = [&](size_t b){ off = (off + 255) & ~(size_t)255; size_t o = off; off += b; return o; };
  size_t o_bi   = alloc((size_t)M_EDGEP*KP*2);           // 28.90 MB
  size_t o_XLXR = alloc((size_t)M_NODEP*1024*2);         // 20.97 MB
  size_t o_hb   = alloc((size_t)M_NODEP*512*2);          // 10.49 MB
  size_t o_eab  = alloc((size_t)E_AUGP*32*2);            // 3.85 MB
  size_t o_WTa  = alloc((size_t)1327104*2);              // 2.65 MB
  size_t o_WeTa = alloc((size_t)57344*2);
  size_t o_WtA  = alloc((size_t)8704*512*2);             // 8.91 MB
  size_t o_EEP  = alloc((size_t)90000000);               // EE (61.6) | P-chunk (89.1) | m1
  size_t o_Wm1T = alloc((size_t)384*KP*2);
  size_t o_Wm2T = alloc((size_t)128*KP*2);
  size_t o_bm1p = alloc(384*4);
  size_t o_bm2p = alloc(128*4);
  size_t o_ma   = alloc((size_t)N_NODES*ED*4);
  size_t o_cnt  = alloc(40000);
  size_t o_rp   = alloc(40004);
  size_t o_fill = alloc(40000);
  size_t o_csr  = alloc(240000);
  if (off > ws_size){
    fprintf(stderr, "kernel_launch: workspace too small: need %zu have %zu\n", off, ws_size);
    return;
  }

  float* meanat = (float*)(ws + o_ma);
  float* cntF   = (float*)(ws + o_cnt);
  int*   rowptr = (int*)(ws + o_rp);
  int*   fill   = (int*)(ws + o_fill);
  int*   csr    = (int*)(ws + o_csr);
  __hip_bfloat16* XLXR = (__hip_bfloat16*)(ws + o_XLXR);
  __hip_bfloat16* hb   = (__hip_bfloat16*)(ws + o_hb);
  __hip_bfloat16* eab  = (__hip_bfloat16*)(ws + o_eab);
  __hip_bfloat16* WTa  = (__hip_bfloat16*)(ws + o_WTa);
  __hip_bfloat16* WeTa = (__hip_bfloat16*)(ws + o_WeTa);
  __hip_bfloat16* WtA  = (__hip_bfloat16*)(ws + o_WtA);
  __half*        EE    = (__half*)(ws + o_EEP);
  __hip_bfloat16* P    = (__hip_bfloat16*)(ws + o_EEP);
  __hip_bfloat16* Wm1T = (__hip_bfloat16*)(ws + o_Wm1T);
  __hip_bfloat16* Wm2T = (__hip_bfloat16*)(ws + o_Wm2T);
  float* bm1p = (float*)(ws + o_bm1p);
  float* bm2p = (float*)(ws + o_bm2p);
  __hip_bfloat16* bi = (__hip_bfloat16*)(ws + o_bi);
  __hip_bfloat16* m1 = (__hip_bfloat16*)(ws + o_EEP);

  // mean_attr + CSR build
  hipMemsetAsync(ws + o_ma, 0, (o_cnt - o_ma) + 40000, stream);
  hipMemsetAsync(ws + o_fill, 0, 40000, stream);
  edge_attr_sum_k<<<3125, 256, 0, stream>>>(ea, ei, meanat, cntF);
  mean_div_k<<<625, 256, 0, stream>>>(meanat, cntF);
  scan_k<<<1, 1024, 0, stream>>>(cntF, rowptr);
  scatter_k<<<235, 256, 0, stream>>>(ei, rowptr, fill, csr);

  // casts + all weight prep upfront
  cast_h_k<<<(M_NODEP*32 + 255)/256, 256, 0, stream>>>(x, hb, 32);
  cast_ea_k<<<(E_AUGP*32 + 255)/256, 256, 0, stream>>>(ea, meanat, eab);
  prep_weights_k<<<5184, 256, 0, stream>>>(
      Wl[0], Wr[0], We[0], Wl[1], Wr[1], We[1], Wl[2], Wr[2], We[2], Wl[3], Wr[3], We[3],
      Wm1, bm1, Wm2, bm2, WTa, WeTa, Wm1T, Wm2T, bm1p, bm2p);
  wbi_transpose_k<<<(BI_OUT*1024*ED + 255)/256, 256, 0, stream>>>(Wbi, WtA);

  const int dins[4]  = {32, 256, 512, 512};
  const int douts[4] = {256, 512, 512, 512};
  const int wtOff[4] = {0, 16384, 278528, 802816};
  const int weOff[4] = {0, 8192, 24576, 40960};
  for (int L = 0; L < 4; ++L){
    int din = dins[L], dn = douts[L];
    if (L == 0){
      gemm_k32_k<__hip_bfloat16><<<M_NODEP/128, 256, 0, stream>>>(
          hb, WTa, XLXR, N_NODES, 4, 32, 512);
    } else {
      dim3 g1(M_NODEP/128, 2*dn/128);
      mfma_gemm_k<__hip_bfloat16,false,false><<<g1, 256, 0, stream>>>(
          hb, WTa + wtOff[L], XLXR, nullptr, N_NODES, din, din, 2*dn);
    }
    gemm_k32_k<__half><<<E_AUGP/128, 256, 0, stream>>>(
        eab, WeTa + weOff[L], EE, E_AUG, dn/128, 32, dn);
    if (dn == 256)
      gat_fused_k<256,true><<<2500, 256, 0, stream>>>(XLXR, EE, ei, rowptr, csr, att[L], bia[L], hb);
    else if (L == 3)
      gat_fused_k<512,false><<<2500, 256, 0, stream>>>(XLXR, EE, ei, rowptr, csr, att[L], bia[L], hb);
    else
      gat_fused_k<512,true><<<2500, 256, 0, stream>>>(XLXR, EE, ei, rowptr, csr, att[L], bia[L], hb);
  }
  // hb holds final node embeddings [M_NODEP x 512] bf16

  // merged PL|PR GEMM per chunk (2 chunks of 136 k's): N = 4352, then bilinear
  const int kbs[2]      = {0, 136};
  const size_t baseE[2] = {0, 2228224};        // chunk elem offsets in WtA (4352*512)
  for (int c = 0; c < 2; ++c){
    dim3 gp(M_NODEP/128, 4352/128);
    mfma_gemm_k<__hip_bfloat16,false,false><<<gp, 256, 0, stream>>>(
        hb, WtA + baseE[c], P, nullptr, N_NODES, 512, 512, 4352);
    bi_k<<<(E_AUG*68 + 255)/256, 256, 0, stream>>>(P, ea, ei, csr, bbi, bi, kbs[c]);
  }

  dim3 gm1(M_EDGEP/128, 3);
  mfma_gemm_k<__hip_bfloat16,true,true><<<gm1, 256, 0, stream>>>(bi, Wm1T, m1, bm1p, M_EDGEP, KP, KP, 384);
  mlp2_out_k<<<M_EDGEP/128, 256, 0, stream>>>(m1, Wm2T, bm2p, Wm3, bm3, out, N_EDGES, KP, 384);
}

// Round 15
// 608.256 us; speedup vs baseline: 1.0644x; 1.0025x over previous
//
#include <hip/hip_runtime.h>
#include <hip/hip_bf16.h>
#include <hip/hip_fp16.h>
#include <cstdio>

#define N_NODES 10000
#define M_NODEP 10240            // 80*128
#define N_EDGES 50000
#define M_EDGEP 50176            // 392*128
#define E_AUG   60000
#define E_AUGP  60160            // 470*128
#define ED      16
#define BI_OUT  272
#define KP      288              // 272 padded to 9*32

typedef __attribute__((ext_vector_type(8))) short s16x8;   // 8 bf16 (4 VGPRs)
typedef __attribute__((ext_vector_type(4))) short s16x4;
typedef __attribute__((ext_vector_type(8))) _Float16 h16x8;
typedef __attribute__((ext_vector_type(4))) _Float16 h16x4;
typedef __attribute__((ext_vector_type(4))) float f32x4;

__device__ inline void stc(float* p, float v){ *p = v; }
__device__ inline void stc(__hip_bfloat16* p, float v){ *p = __float2bfloat16(v); }
__device__ inline void stc(__half* p, float v){ *p = __float2half(v); }
__device__ inline float bf2f(short s){ return __uint_as_float(((unsigned)(unsigned short)s) << 16); }
__device__ inline short f2bf(float f){ __hip_bfloat16 h = __float2bfloat16(f); return *(short*)&h; }

// async global->LDS, 16 B per lane; LDS dest is wave-uniform base (lane*16 implicit)
__device__ __forceinline__ void gl2lds16(const void* g, void* l){
  __builtin_amdgcn_global_load_lds((const __attribute__((address_space(1))) void*)g,
                                   (__attribute__((address_space(3))) void*)l, 16, 0, 0);
}

// B pre-swizzle index: logical B^T element (row n, col k) of a matrix with
// kSteps = K/32  ->  element offset ((nb*kSteps + s)*8 + f)*512 + lane*8 + ii
// where nb=n>>7, f=(n>>4)&7, r=n&15, s=k>>5, q=(k>>3)&3, ii=k&7, lane=q*16+r.
__device__ inline size_t preidx(int n, int k, int kSteps){
  int nb = n >> 7, f = (n >> 4) & 7, r = n & 15;
  int s = k >> 5, q = (k >> 3) & 3, ii = k & 7;
  return ((((size_t)nb*kSteps + s)*8 + f)*64 + q*16 + r)*8 + ii;
}

// ---------- degree count (real edges only) ----------
__global__ void count_k(const int* __restrict__ ei, int* __restrict__ cnt){
  int e = blockIdx.x*256 + threadIdx.x;
  if (e >= N_EDGES) return;
  atomicAdd(&cnt[ei[N_EDGES + e]], 1);
}

// ---------- CSR build ----------
__global__ void scan_k(const int* __restrict__ cnt, int* __restrict__ rowptr){
  __shared__ int s[1024];
  int tid = threadIdx.x;
  int loc[10]; int sum = 0;
  #pragma unroll
  for (int k = 0; k < 10; ++k){
    int i = tid*10 + k;
    int v = (i < N_NODES) ? (cnt[i] + 1) : 0;   // +1 self loop
    loc[k] = sum; sum += v;
  }
  s[tid] = sum; __syncthreads();
  for (int off = 1; off < 1024; off <<= 1){
    int t2 = (tid >= off) ? s[tid-off] : 0;
    __syncthreads();
    s[tid] += t2;
    __syncthreads();
  }
  int pre = s[tid] - sum;
  #pragma unroll
  for (int k = 0; k < 10; ++k){
    int i = tid*10 + k;
    if (i < N_NODES) rowptr[i] = pre + loc[k];
  }
  if (tid == 1023) rowptr[N_NODES] = s[1023];
}

__global__ void scatter_k(const int* __restrict__ ei, const int* __restrict__ rowptr,
                          int* __restrict__ fill, int* __restrict__ csr){
  int e = blockIdx.x*256 + threadIdx.x;
  if (e >= E_AUG) return;
  int dst = (e < N_EDGES) ? ei[N_EDGES+e] : (e - N_EDGES);
  int pos = rowptr[dst] + atomicAdd(&fill[dst], 1);
  csr[pos] = e;
}

// ---------- mean edge_attr per dst via CSR (no atomics) ----------
__global__ void meanat_csr_k(const float* __restrict__ ea, const int* __restrict__ rowptr,
                             const int* __restrict__ csr, float* __restrict__ meanat){
  int g = blockIdx.x*256 + threadIdx.x;
  int n = g >> 4, j = g & 15;
  if (n >= N_NODES) return;
  int r0 = rowptr[n], r1 = rowptr[n+1];
  float acc = 0.f; int c = 0;
  for (int p = r0; p < r1; ++p){
    int e = csr[p];
    if (e < N_EDGES){ acc += ea[(size_t)e*ED + j]; ++c; }
  }
  meanat[(size_t)n*ED + j] = acc / fmaxf((float)c, 1.f);
}

// ---------- MFMA bf16 GEMM, 128x128 tile, B from pre-swizzled global ----------
// (round-11 verified). A: LDS double-buffer, single barrier per 32-k iter;
// XOR-quad swizzle. B: fragment-order (preidx), prefetched one step ahead.
template<typename TC, bool BIAS, bool RELU>
__global__ __launch_bounds__(256)
void mfma_gemm_k(const __hip_bfloat16* __restrict__ A, const __hip_bfloat16* __restrict__ Bp,
                 TC* __restrict__ C, const float* __restrict__ bias,
                 int Mstore, int K, int lda, int ldc){
  __shared__ __align__(16) __hip_bfloat16 Asm[2][4096];
  const int tid = threadIdx.x;
  const int lane = tid & 63, wave = tid >> 6;
  const int wm = (wave >> 1) * 64, wn = (wave & 1) * 64;
  const int m0 = blockIdx.x * 128, n0 = blockIdx.y * 128;
  const int quad = lane >> 4, r16 = lane & 15;
  const int kSteps = K >> 5;

  f32x4 acc[4][4];
  #pragma unroll
  for (int i = 0; i < 4; ++i)
    #pragma unroll
    for (int j = 0; j < 4; ++j)
      acc[i][j] = (f32x4){0.f, 0.f, 0.f, 0.f};

  const int rl = lane >> 2, cq = lane & 3;
  const int row0 = wave*32 + rl;
  const int qg = (cq - ((row0 >> 1) & 3)) & 3;
  const __hip_bfloat16* ga0 = &A[(size_t)(m0 + row0)*lda + qg*8];
  const __hip_bfloat16* ga1 = &A[(size_t)(m0 + row0 + 16)*lda + qg*8];
  const int aoff0 = (wave*32)*32, aoff1 = (wave*32 + 16)*32;

  const __hip_bfloat16* gB = Bp + (((size_t)blockIdx.y*kSteps)*8 + (wn >> 4))*512 + (size_t)lane*8;

  gl2lds16(ga0, &Asm[0][aoff0]);
  gl2lds16(ga1, &Asm[0][aoff1]);
  s16x8 bcur[4], bnxt[4];
  #pragma unroll
  for (int j = 0; j < 4; ++j) bcur[j] = *(const s16x8*)(gB + j*512);

  for (int s = 0; s < kSteps; ++s){
    __syncthreads();
    if (s + 1 < kSteps){
      int k0 = (s + 1) * 32;
      gl2lds16(ga0 + k0, &Asm[(s+1)&1][aoff0]);
      gl2lds16(ga1 + k0, &Asm[(s+1)&1][aoff1]);
      const __hip_bfloat16* gBn = gB + (size_t)(s+1)*4096;
      #pragma unroll
      for (int j = 0; j < 4; ++j) bnxt[j] = *(const s16x8*)(gBn + j*512);
    }
    s16x8 af[4];
    #pragma unroll
    for (int i = 0; i < 4; ++i){
      int row = wm + i*16 + r16;
      af[i] = *(const s16x8*)&Asm[s & 1][row*32 + (((quad + (row >> 1)) & 3) << 3)];
    }
    #pragma unroll
    for (int i = 0; i < 4; ++i)
      #pragma unroll
      for (int j = 0; j < 4; ++j)
        acc[i][j] = __builtin_amdgcn_mfma_f32_16x16x32_bf16(af[i], bcur[j], acc[i][j], 0, 0, 0);
    #pragma unroll
    for (int j = 0; j < 4; ++j) bcur[j] = bnxt[j];
  }
  #pragma unroll
  for (int i = 0; i < 4; ++i){
    #pragma unroll
    for (int reg = 0; reg < 4; ++reg){
      int gr = m0 + wm + i*16 + quad*4 + reg;
      if (gr >= Mstore) continue;
      #pragma unroll
      for (int j = 0; j < 4; ++j){
        int gc = n0 + wn + j*16 + r16;
        float v = acc[i][j][reg];
        if (BIAS) v += bias[gc];
        if (RELU) v = fmaxf(v, 0.f);
        stc(&C[(size_t)gr*ldc + gc], v);
      }
    }
  }
}

// ---------- K=32 GEMM, multi-N-tile per block (A staged & frags loaded once) ----------
template<typename TC>
__global__ __launch_bounds__(256)
void gemm_k32_k(const __hip_bfloat16* __restrict__ A, const __hip_bfloat16* __restrict__ Bp,
                TC* __restrict__ C, int Mstore, int Ntiles, int lda, int ldc){
  __shared__ __align__(16) __hip_bfloat16 Asm[4096];
  const int tid = threadIdx.x;
  const int lane = tid & 63, wave = tid >> 6;
  const int wm = (wave >> 1) * 64, wn = (wave & 1) * 64;
  const int m0 = blockIdx.x * 128;
  const int quad = lane >> 4, r16 = lane & 15;

  const int rl = lane >> 2, cq = lane & 3;
  const int row0 = wave*32 + rl;
  const int qg = (cq - ((row0 >> 1) & 3)) & 3;
  gl2lds16(&A[(size_t)(m0 + row0)*lda + qg*8],      &Asm[(wave*32)*32]);
  gl2lds16(&A[(size_t)(m0 + row0 + 16)*lda + qg*8], &Asm[(wave*32 + 16)*32]);
  __syncthreads();
  s16x8 af[4];
  #pragma unroll
  for (int i = 0; i < 4; ++i){
    int row = wm + i*16 + r16;
    af[i] = *(const s16x8*)&Asm[row*32 + (((quad + (row >> 1)) & 3) << 3)];
  }

  const __hip_bfloat16* gB = Bp + (size_t)(wn >> 4)*512 + (size_t)lane*8;
  s16x8 bcur[4], bnxt[4];
  #pragma unroll
  for (int j = 0; j < 4; ++j) bcur[j] = *(const s16x8*)(gB + j*512);

  for (int nt = 0; nt < Ntiles; ++nt){
    if (nt + 1 < Ntiles){
      const __hip_bfloat16* gBn = gB + (size_t)(nt+1)*4096;
      #pragma unroll
      for (int j = 0; j < 4; ++j) bnxt[j] = *(const s16x8*)(gBn + j*512);
    }
    f32x4 acc[4][4];
    #pragma unroll
    for (int i = 0; i < 4; ++i)
      #pragma unroll
      for (int j = 0; j < 4; ++j)
        acc[i][j] = (f32x4){0.f, 0.f, 0.f, 0.f};
    #pragma unroll
    for (int i = 0; i < 4; ++i)
      #pragma unroll
      for (int j = 0; j < 4; ++j)
        acc[i][j] = __builtin_amdgcn_mfma_f32_16x16x32_bf16(af[i], bcur[j], acc[i][j], 0, 0, 0);
    int n0 = nt*128;
    #pragma unroll
    for (int i = 0; i < 4; ++i){
      #pragma unroll
      for (int reg = 0; reg < 4; ++reg){
        int gr = m0 + wm + i*16 + quad*4 + reg;
        if (gr >= Mstore) continue;
        #pragma unroll
        for (int j = 0; j < 4; ++j)
          stc(&C[(size_t)gr*ldc + n0 + wn + j*16 + r16], acc[i][j][reg]);
      }
    }
    #pragma unroll
    for (int j = 0; j < 4; ++j) bcur[j] = bnxt[j];
  }
}

// ---------- m2 GEMM with fused Wm3-dot + sigmoid epilogue ----------
__global__ __launch_bounds__(256)
void mlp2_out_k(const __hip_bfloat16* __restrict__ A, const __hip_bfloat16* __restrict__ Bp,
                const float* __restrict__ bias, const float* __restrict__ Wm3,
                const float* __restrict__ bm3, float* __restrict__ out,
                int Mstore, int K, int lda){
  __shared__ __align__(16) __hip_bfloat16 Asm[2][4096];
  const int tid = threadIdx.x;
  const int lane = tid & 63, wave = tid >> 6;
  const int wm = (wave >> 1) * 64, wn = (wave & 1) * 64;
  const int m0 = blockIdx.x * 128;
  const int quad = lane >> 4, r16 = lane & 15;
  const int kSteps = K >> 5;

  f32x4 acc[4][2];
  #pragma unroll
  for (int i = 0; i < 4; ++i)
    #pragma unroll
    for (int j = 0; j < 2; ++j)
      acc[i][j] = (f32x4){0.f, 0.f, 0.f, 0.f};

  const int rl = lane >> 2, cq = lane & 3;
  const int row0 = wave*32 + rl;
  const int qg = (cq - ((row0 >> 1) & 3)) & 3;
  const __hip_bfloat16* ga0 = &A[(size_t)(m0 + row0)*lda + qg*8];
  const __hip_bfloat16* ga1 = &A[(size_t)(m0 + row0 + 16)*lda + qg*8];
  const int aoff0 = (wave*32)*32, aoff1 = (wave*32 + 16)*32;

  const __hip_bfloat16* gB = Bp + (size_t)(wn >> 4)*512 + (size_t)lane*8;

  gl2lds16(ga0, &Asm[0][aoff0]);
  gl2lds16(ga1, &Asm[0][aoff1]);
  s16x8 bcur[2], bnxt[2];
  #pragma unroll
  for (int j = 0; j < 2; ++j) bcur[j] = *(const s16x8*)(gB + j*512);

  for (int s = 0; s < kSteps; ++s){
    __syncthreads();
    if (s + 1 < kSteps){
      int k0 = (s + 1) * 32;
      gl2lds16(ga0 + k0, &Asm[(s+1)&1][aoff0]);
      gl2lds16(ga1 + k0, &Asm[(s+1)&1][aoff1]);
      const __hip_bfloat16* gBn = gB + (size_t)(s+1)*4096;
      #pragma unroll
      for (int j = 0; j < 2; ++j) bnxt[j] = *(const s16x8*)(gBn + j*512);
    }
    s16x8 af[4];
    #pragma unroll
    for (int i = 0; i < 4; ++i){
      int row = wm + i*16 + r16;
      af[i] = *(const s16x8*)&Asm[s & 1][row*32 + (((quad + (row >> 1)) & 3) << 3)];
    }
    #pragma unroll
    for (int i = 0; i < 4; ++i)
      #pragma unroll
      for (int j = 0; j < 2; ++j)
        acc[i][j] = __builtin_amdgcn_mfma_f32_16x16x32_bf16(af[i], bcur[j], acc[i][j], 0, 0, 0);
    #pragma unroll
    for (int j = 0; j < 2; ++j) bcur[j] = bnxt[j];
  }
  if (wn == 0){
    float w3a = Wm3[r16], w3b = Wm3[16 + r16];
    float ba = bias[r16], bb = bias[16 + r16];
    #pragma unroll
    for (int i = 0; i < 4; ++i){
      #pragma unroll
      for (int reg = 0; reg < 4; ++reg){
        int gr = m0 + wm + i*16 + quad*4 + reg;
        float v0 = fmaxf(acc[i][0][reg] + ba, 0.f);
        float v1 = fmaxf(acc[i][1][reg] + bb, 0.f);
        float dot = v0*w3a + v1*w3b;
        #pragma unroll
        for (int off = 1; off < 16; off <<= 1) dot += __shfl_xor(dot, off, 64);
        if (r16 == 0 && gr < Mstore)
          out[gr] = 1.0f/(1.0f + __expf(-(dot + bm3[0])));
      }
    }
  }
}

// ---------- fused prep: cast_h | cast_ea | weight swizzles | wbi transpose ----------
__global__ void prep_all_k(
    const float* __restrict__ x, const float* __restrict__ ea, const float* __restrict__ meanat,
    const float* __restrict__ Wl0, const float* __restrict__ Wr0, const float* __restrict__ We0,
    const float* __restrict__ Wl1, const float* __restrict__ Wr1, const float* __restrict__ We1,
    const float* __restrict__ Wl2, const float* __restrict__ Wr2, const float* __restrict__ We2,
    const float* __restrict__ Wl3, const float* __restrict__ Wr3, const float* __restrict__ We3,
    const float* __restrict__ Wm1, const float* __restrict__ bm1,
    const float* __restrict__ Wm2, const float* __restrict__ bm2,
    const float* __restrict__ Wbi,
    __hip_bfloat16* __restrict__ hb, __hip_bfloat16* __restrict__ eab,
    __hip_bfloat16* __restrict__ WTa, __hip_bfloat16* __restrict__ WeTa,
    __hip_bfloat16* __restrict__ Wm1T, __hip_bfloat16* __restrict__ Wm2T,
    float* __restrict__ bm1p, float* __restrict__ bm2p,
    __hip_bfloat16* __restrict__ WtA){
  int b = blockIdx.x;
  if (b < 1280){
    int t = b*256 + threadIdx.x;                 // cast_h: x -> hb [M_NODEP x 32]
    int r = t >> 5;
    hb[t] = (r < N_NODES) ? __float2bfloat16(x[t]) : __float2bfloat16(0.f);
    return;
  }
  b -= 1280;
  if (b < 7520){
    int t = b*256 + threadIdx.x;                 // cast_ea: -> eab [E_AUGP x 32]
    if (t < E_AUGP*32){
      int e = t >> 5, j = t & 31;
      float v = 0.f;
      if (j < 16){
        if (e < N_EDGES) v = ea[(size_t)e*ED + j];
        else if (e < E_AUG) v = meanat[(size_t)(e - N_EDGES)*ED + j];
      }
      eab[t] = __float2bfloat16(v);
    }
    return;
  }
  b -= 7520;
  if (b < 5184){
    int t = b*256 + threadIdx.x;                 // weight swizzles
    if (t < 16384){
      int half = t >> 13, r = t & 8191, i = r >> 8, j = r & 255;
      WTa[preidx(half*256 + j, i, 1)] = __float2bfloat16(half ? Wr0[r] : Wl0[r]);
    } else if (t < 278528){
      int u = t - 16384, half = u >> 17, r = u & 131071, i = r >> 9, j = r & 511;
      WTa[16384 + preidx(half*512 + j, i, 8)] = __float2bfloat16(half ? Wr1[r] : Wl1[r]);
    } else if (t < 802816){
      int u = t - 278528, half = u >> 18, r = u & 262143, i = r >> 9, j = r & 511;
      WTa[278528 + preidx(half*512 + j, i, 16)] = __float2bfloat16(half ? Wr2[r] : Wl2[r]);
    } else if (t < 1327104){
      int u = t - 802816, half = u >> 18, r = u & 262143, i = r >> 9, j = r & 511;
      WTa[802816 + preidx(half*512 + j, i, 16)] = __float2bfloat16(half ? Wr3[r] : Wl3[r]);
    }
    if (t < 8192){
      int n = t >> 5, k = t & 31;
      WeTa[preidx(n, k, 1)] = __float2bfloat16((k < 16) ? We0[k*256 + n] : 0.f);
    } else if (t < 24576){
      int u = t - 8192, n = u >> 5, k = u & 31;
      WeTa[8192 + preidx(n, k, 1)] = __float2bfloat16((k < 16) ? We1[k*512 + n] : 0.f);
    } else if (t < 40960){
      int u = t - 24576, n = u >> 5, k = u & 31;
      WeTa[24576 + preidx(n, k, 1)] = __float2bfloat16((k < 16) ? We2[k*512 + n] : 0.f);
    } else if (t < 57344){
      int u = t - 40960, n = u >> 5, k = u & 31;
      WeTa[40960 + preidx(n, k, 1)] = __float2bfloat16((k < 16) ? We3[k*512 + n] : 0.f);
    }
    if (t < 384*KP){
      int n = t / KP, k = t - n*KP;
      Wm1T[preidx(n, k, 9)] = __float2bfloat16((n < BI_OUT && k < BI_OUT) ? Wm1[(size_t)k*BI_OUT + n] : 0.f);
    }
    if (t < 128*KP){
      int n = t / KP, k = t - n*KP;
      Wm2T[preidx(n, k, 9)] = __float2bfloat16((n < 32 && k < BI_OUT) ? Wm2[(size_t)k*32 + n] : 0.f);
    }
    if (t < 384) bm1p[t] = (t < BI_OUT) ? bm1[t] : 0.f;
    if (t < 128) bm2p[t] = (t < 32) ? bm2[t] : 0.f;
    return;
  }
  b -= 5184;
  {
    int t = b*256 + threadIdx.x;                 // wbi transpose (2 chunks of 136 k)
    if (t >= BI_OUT*1024*ED) return;
    int k = t >> 14, r = t & 16383;
    int i = r >> 4, j = r & 15;
    int c = (k < 136) ? 0 : 1;
    int kb = c*136;
    const int cw = 2176;
    size_t baseE = (size_t)c * 2228224;          // 4352*512
    int row = ((i >= 512) ? cw : 0) + (k - kb)*16 + j;
    WtA[baseE + preidx(row, i & 511, 16)] = __float2bfloat16(Wbi[t]);
  }
}

// ---------- fused GAT: one-pass online softmax + aggregate, 1 wave per dst ----------
template<int DOUT, bool RELU>
__global__ __launch_bounds__(256)
void gat_fused_k(const __hip_bfloat16* __restrict__ XLXR, const __half* __restrict__ EE,
                 const int* __restrict__ ei, const int* __restrict__ rowptr,
                 const int* __restrict__ csr, const float* __restrict__ att,
                 const float* __restrict__ b, __hip_bfloat16* __restrict__ hb){
  constexpr int NI = DOUT/64;
  constexpr int W2 = 2*DOUT;
  int wave = threadIdx.x >> 6, lane = threadIdx.x & 63;
  int n = blockIdx.x*4 + wave;
  if (n >= N_NODES) return;
  int r0 = rowptr[n], r1 = rowptr[n+1];
  int pp = r0 + lane;
  int e_l = 0, s_l = 0;
  if (pp < r1){
    e_l = csr[pp];
    s_l = (e_l < N_EDGES) ? ei[e_l] : (e_l - N_EDGES);
  }
  float xr[NI], at[NI], acc[NI];
  #pragma unroll
  for (int i = 0; i < NI; ++i){
    int d = lane*NI + i;
    xr[i]  = bf2f(((const short*)XLXR)[(size_t)n*W2 + DOUT + d]);
    at[i]  = att[d];
    acc[i] = 0.f;
  }
  auto getes = [&](int p, int &e, int &s){
    int idx = p - r0;
    if (idx < 64){ e = __shfl(e_l, idx, 64); s = __shfl(s_l, idx, 64); }
    else { e = csr[p]; s = (e < N_EDGES) ? ei[e] : (e - N_EDGES); }
  };
  float mrun = -1e30f, den = 0.f;
  int p = r0;
  for (; p + 3 < r1; p += 4){
    int ee4[4], ss4[4];
    #pragma unroll
    for (int u = 0; u < 4; ++u) getes(p + u, ee4[u], ss4[u]);
    float xl[4][NI], a[4];
    #pragma unroll
    for (int u = 0; u < 4; ++u){
      const short* xp = (const short*)XLXR + (size_t)ss4[u]*W2 + lane*NI;
      const _Float16* ep = (const _Float16*)EE + (size_t)ee4[u]*DOUT + lane*NI;
      float au = 0.f;
      if constexpr (NI == 8){
        s16x8 xv = *(const s16x8*)xp; h16x8 ev = *(const h16x8*)ep;
        #pragma unroll
        for (int i = 0; i < 8; ++i){
          xl[u][i] = bf2f(xv[i]);
          float v = xl[u][i] + xr[i] + (float)ev[i];
          v = (v > 0.f) ? v : 0.2f*v;
          au += at[i]*v;
        }
      } else {
        s16x4 xv = *(const s16x4*)xp; h16x4 ev = *(const h16x4*)ep;
        #pragma unroll
        for (int i = 0; i < 4; ++i){
          xl[u][i] = bf2f(xv[i]);
          float v = xl[u][i] + xr[i] + (float)ev[i];
          v = (v > 0.f) ? v : 0.2f*v;
          au += at[i]*v;
        }
      }
      a[u] = au;
    }
    #pragma unroll
    for (int off = 32; off; off >>= 1){
      #pragma unroll
      for (int u = 0; u < 4; ++u) a[u] += __shfl_xor(a[u], off, 64);
    }
    float mnew = fmaxf(mrun, fmaxf(fmaxf(a[0], a[1]), fmaxf(a[2], a[3])));
    float sc = __expf(mrun - mnew);
    float w0 = __expf(a[0] - mnew), w1 = __expf(a[1] - mnew);
    float w2 = __expf(a[2] - mnew), w3 = __expf(a[3] - mnew);
    den = den*sc + w0 + w1 + w2 + w3;
    #pragma unroll
    for (int i = 0; i < NI; ++i)
      acc[i] = acc[i]*sc + w0*xl[0][i] + w1*xl[1][i] + w2*xl[2][i] + w3*xl[3][i];
    mrun = mnew;
  }
  for (; p + 1 < r1; p += 2){
    int e0, s0, e1, s1;
    getes(p, e0, s0); getes(p + 1, e1, s1);
    const short* xp0 = (const short*)XLXR + (size_t)s0*W2 + lane*NI;
    const short* xp1 = (const short*)XLXR + (size_t)s1*W2 + lane*NI;
    const _Float16* ep0 = (const _Float16*)EE + (size_t)e0*DOUT + lane*NI;
    const _Float16* ep1 = (const _Float16*)EE + (size_t)e1*DOUT + lane*NI;
    float xl0[NI], xl1[NI];
    float a0 = 0.f, a1 = 0.f;
    #pragma unroll
    for (int i = 0; i < NI; ++i){
      xl0[i] = bf2f(xp0[i]); xl1[i] = bf2f(xp1[i]);
      float v0 = xl0[i] + xr[i] + (float)ep0[i];
      float v1 = xl1[i] + xr[i] + (float)ep1[i];
      v0 = (v0 > 0.f) ? v0 : 0.2f*v0;
      v1 = (v1 > 0.f) ? v1 : 0.2f*v1;
      a0 += at[i]*v0; a1 += at[i]*v1;
    }
    #pragma unroll
    for (int off = 32; off; off >>= 1){
      a0 += __shfl_xor(a0, off, 64);
      a1 += __shfl_xor(a1, off, 64);
    }
    float mnew = fmaxf(mrun, fmaxf(a0, a1));
    float sc = __expf(mrun - mnew);
    float w0 = __expf(a0 - mnew);
    float w1 = __expf(a1 - mnew);
    den = den*sc + w0 + w1;
    #pragma unroll
    for (int i = 0; i < NI; ++i) acc[i] = acc[i]*sc + w0*xl0[i] + w1*xl1[i];
    mrun = mnew;
  }
  if (p < r1){
    int e0, s0;
    getes(p, e0, s0);
    const short* xp0 = (const short*)XLXR + (size_t)s0*W2 + lane*NI;
    const _Float16* ep0 = (const _Float16*)EE + (size_t)e0*DOUT + lane*NI;
    float xl0[NI];
    float a0 = 0.f;
    #pragma unroll
    for (int i = 0; i < NI; ++i){
      xl0[i] = bf2f(xp0[i]);
      float v0 = xl0[i] + xr[i] + (float)ep0[i];
      v0 = (v0 > 0.f) ? v0 : 0.2f*v0;
      a0 += at[i]*v0;
    }
    #pragma unroll
    for (int off = 32; off; off >>= 1) a0 += __shfl_xor(a0, off, 64);
    float mnew = fmaxf(mrun, a0);
    float sc = __expf(mrun - mnew);
    float w0 = __expf(a0 - mnew);
    den = den*sc + w0;
    #pragma unroll
    for (int i = 0; i < NI; ++i) acc[i] = acc[i]*sc + w0*xl0[i];
    mrun = mnew;
  }
  float dinv = 1.0f / fmaxf(den, 1e-16f);
  if constexpr (NI == 8){
    s16x8 o;
    #pragma unroll
    for (int i = 0; i < 8; ++i){
      float v = b[lane*8 + i] + acc[i]*dinv;
      o[i] = f2bf(RELU ? fmaxf(v, 0.f) : v);
    }
    *(s16x8*)((short*)hb + (size_t)n*DOUT + lane*8) = o;
  } else {
    s16x4 o;
    #pragma unroll
    for (int i = 0; i < 4; ++i){
      float v = b[lane*4 + i] + acc[i]*dinv;
      o[i] = f2bf(RELU ? fmaxf(v, 0.f) : v);
    }
    *(s16x4*)((short*)hb + (size_t)n*DOUT + lane*4) = o;
  }
}

// ---------- per-edge bilinear, dst-ordered via CSR; 2 adjacent k per thread ----------
__global__ void bi_k(const __hip_bfloat16* __restrict__ P, const float* __restrict__ ea,
                     const int* __restrict__ ei, const int* __restrict__ csr,
                     const float* __restrict__ bbi, __hip_bfloat16* __restrict__ bi,
                     int kb){
  const int KH = 68;                           // 136/2 pairs
  const int cw = 2176, w2 = 4352;
  int g = blockIdx.x*256 + threadIdx.x;
  if (g >= E_AUG*KH) return;
  int p = g / KH, kp = g - p*KH;
  int k = kp*2;
  int e = csr[p];
  if (e >= N_EDGES) return;                    // self-loop pseudo-edge: no bi output
  int src = ei[e], dst = ei[N_EDGES+e];
  const s16x8* pl = (const s16x8*)(P + (size_t)src*w2 + k*ED);
  const s16x8* pr = (const s16x8*)(P + (size_t)dst*w2 + cw + k*ED);
  s16x8 pl0 = pl[0], pl1 = pl[1], pl2 = pl[2], pl3 = pl[3];
  s16x8 pr0 = pr[0], pr1 = pr[1], pr2 = pr[2], pr3 = pr[3];
  const float* eap = ea + (size_t)e*ED;
  float s0 = 0.f, s1 = 0.f;
  #pragma unroll
  for (int j = 0; j < 8; ++j){
    s0 += eap[j]  *(bf2f(pl0[j]) + bf2f(pr0[j]));
    s0 += eap[j+8]*(bf2f(pl1[j]) + bf2f(pr1[j]));
    s1 += eap[j]  *(bf2f(pl2[j]) + bf2f(pr2[j]));
    s1 += eap[j+8]*(bf2f(pl3[j]) + bf2f(pr3[j]));
  }
  int kg = kb + k;
  short2 o;
  o.x = f2bf(s0 + bbi[kg]);
  o.y = f2bf(s1 + bbi[kg+1]);
  *(short2*)((short*)bi + (size_t)e*KP + kg) = o;
}

extern "C" void kernel_launch(void* const* d_in, const int* in_sizes, int n_in,
                              void* d_out, int out_size, void* d_ws, size_t ws_size,
                              hipStream_t stream) {
  const float* x   = (const float*)d_in[0];
  const float* ea  = (const float*)d_in[1];
  const int*   ei  = (const int*)d_in[2];
  const float* Wl[4]  = {(const float*)d_in[3],(const float*)d_in[8],(const float*)d_in[13],(const float*)d_in[18]};
  const float* Wr[4]  = {(const float*)d_in[4],(const float*)d_in[9],(const float*)d_in[14],(const float*)d_in[19]};
  const float* We[4]  = {(const float*)d_in[5],(const float*)d_in[10],(const float*)d_in[15],(const float*)d_in[20]};
  const float* att[4] = {(const float*)d_in[6],(const float*)d_in[11],(const float*)d_in[16],(const float*)d_in[21]};
  const float* bia[4] = {(const float*)d_in[7],(const float*)d_in[12],(const float*)d_in[17],(const float*)d_in[22]};
  const float* Wbi = (const float*)d_in[23];
  const float* bbi = (const float*)d_in[24];
  const float* Wm1 = (const float*)d_in[25];
  const float* bm1 = (const float*)d_in[26];
  const float* Wm2 = (const float*)d_in[27];
  const float* bm2 = (const float*)d_in[28];
  const float* Wm3 = (const float*)d_in[29];
  const float* bm3 = (const float*)d_in[30];
  float* out = (float*)d_out;

  char* ws = (char*)d_ws;
  size_t off = 0;
  auto alloc = [&](size_t b){ off = (off + 255) & ~(size_t)255; size_t o = off; off += b; return o; };
  size_t o_bi   = alloc((size_t)M_EDGEP*KP*2);           // 28.90 MB
  size_t o_XLXR = alloc((size_t)M_NODEP*1024*2);         // 20.97 MB
  size_t o_hb   = alloc((size_t)M_NODEP*512*2);          // 10.49 MB
  size_t o_eab  = alloc((size_t)E_AUGP*32*2);            // 3.85 MB
  size_t o_WTa  = alloc((size_t)1327104*2);              // 2.65 MB
  size_t o_WeTa = alloc((size_t)57344*2);
  size_t o_WtA  = alloc((size_t)8704*512*2);             // 8.91 MB
  size_t o_EEP  = alloc((size_t)90000000);               // EE (61.6) | P-chunk (89.1) | m1
  size_t o_Wm1T = alloc((size_t)384*KP*2);
  size_t o_Wm2T = alloc((size_t)128*KP*2);
  size_t o_bm1p = alloc(384*4);
  size_t o_bm2p = alloc(128*4);
  size_t o_ma   = alloc((size_t)N_NODES*ED*4);
  size_t o_cnt  = alloc(40000);
  size_t o_fill = alloc(40000);
  size_t o_rp   = alloc(40004);
  size_t o_csr  = alloc(240000);
  if (off > ws_size){
    fprintf(stderr, "kernel_launch: workspace too small: need %zu have %zu\n", off, ws_size);
    return;
  }

  float* meanat = (float*)(ws + o_ma);
  int*   cnt    = (int*)(ws + o_cnt);
  int*   fill   = (int*)(ws + o_fill);
  int*   rowptr = (int*)(ws + o_rp);
  int*   csr    = (int*)(ws + o_csr);
  __hip_bfloat16* XLXR = (__hip_bfloat16*)(ws + o_XLXR);
  __hip_bfloat16* hb   = (__hip_bfloat16*)(ws + o_hb);
  __hip_bfloat16* eab  = (__hip_bfloat16*)(ws + o_eab);
  __hip_bfloat16* WTa  = (__hip_bfloat16*)(ws + o_WTa);
  __hip_bfloat16* WeTa = (__hip_bfloat16*)(ws + o_WeTa);
  __hip_bfloat16* WtA  = (__hip_bfloat16*)(ws + o_WtA);
  __half*        EE    = (__half*)(ws + o_EEP);
  __hip_bfloat16* P    = (__hip_bfloat16*)(ws + o_EEP);
  __hip_bfloat16* Wm1T = (__hip_bfloat16*)(ws + o_Wm1T);
  __hip_bfloat16* Wm2T = (__hip_bfloat16*)(ws + o_Wm2T);
  float* bm1p = (float*)(ws + o_bm1p);
  float* bm2p = (float*)(ws + o_bm2p);
  __hip_bfloat16* bi = (__hip_bfloat16*)(ws + o_bi);
  __hip_bfloat16* m1 = (__hip_bfloat16*)(ws + o_EEP);

  // CSR build (cnt+fill adjacent -> one memset), then CSR-based mean_attr
  hipMemsetAsync(ws + o_cnt, 0, (o_fill - o_cnt) + 40000, stream);
  count_k<<<(N_EDGES + 255)/256, 256, 0, stream>>>(ei, cnt);
  scan_k<<<1, 1024, 0, stream>>>(cnt, rowptr);
  scatter_k<<<235, 256, 0, stream>>>(ei, rowptr, fill, csr);
  meanat_csr_k<<<625, 256, 0, stream>>>(ea, rowptr, csr, meanat);

  // single fused prep kernel (casts + all weight swizzles)
  prep_all_k<<<1280 + 7520 + 5184 + 17408, 256, 0, stream>>>(
      x, ea, meanat,
      Wl[0], Wr[0], We[0], Wl[1], Wr[1], We[1], Wl[2], Wr[2], We[2], Wl[3], Wr[3], We[3],
      Wm1, bm1, Wm2, bm2, Wbi,
      hb, eab, WTa, WeTa, Wm1T, Wm2T, bm1p, bm2p, WtA);

  const int dins[4]  = {32, 256, 512, 512};
  const int douts[4] = {256, 512, 512, 512};
  const int wtOff[4] = {0, 16384, 278528, 802816};
  const int weOff[4] = {0, 8192, 24576, 40960};
  for (int L = 0; L < 4; ++L){
    int din = dins[L], dn = douts[L];
    if (L == 0){
      gemm_k32_k<__hip_bfloat16><<<M_NODEP/128, 256, 0, stream>>>(
          hb, WTa, XLXR, N_NODES, 4, 32, 512);
    } else {
      dim3 g1(M_NODEP/128, 2*dn/128);
      mfma_gemm_k<__hip_bfloat16,false,false><<<g1, 256, 0, stream>>>(
          hb, WTa + wtOff[L], XLXR, nullptr, N_NODES, din, din, 2*dn);
    }
    gemm_k32_k<__half><<<E_AUGP/128, 256, 0, stream>>>(
        eab, WeTa + weOff[L], EE, E_AUG, dn/128, 32, dn);
    if (dn == 256)
      gat_fused_k<256,true><<<2500, 256, 0, stream>>>(XLXR, EE, ei, rowptr, csr, att[L], bia[L], hb);
    else if (L == 3)
      gat_fused_k<512,false><<<2500, 256, 0, stream>>>(XLXR, EE, ei, rowptr, csr, att[L], bia[L], hb);
    else
      gat_fused_k<512,true><<<2500, 256, 0, stream>>>(XLXR, EE, ei, rowptr, csr, att[L], bia[L], hb);
  }
  // hb holds final node embeddings [M_NODEP x 512] bf16

  // merged PL|PR GEMM per chunk (2 chunks of 136 k's): N = 4352, then bilinear
  const int kbs[2]      = {0, 136};
  const size_t baseE[2] = {0, 2228224};        // chunk elem offsets in WtA (4352*512)
  for (int c = 0; c < 2; ++c){
    dim3 gp(M_NODEP/128, 4352/128);
    mfma_gemm_k<__hip_bfloat16,false,false><<<gp, 256, 0, stream>>>(
        hb, WtA + baseE[c], P, nullptr, N_NODES, 512, 512, 4352);
    bi_k<<<(E_AUG*68 + 255)/256, 256, 0, stream>>>(P, ea, ei, csr, bbi, bi, kbs[c]);
  }

  dim3 gm1(M_EDGEP/128, 3);
  mfma_gemm_k<__hip_bfloat16,true,true><<<gm1, 256, 0, stream>>>(bi, Wm1T, m1, bm1p, M_EDGEP, KP, KP, 384);
  mlp2_out_k<<<M_EDGEP/128, 256, 0, stream>>>(m1, Wm2T, bm2p, Wm3, bm3, out, N_EDGES, KP, 384);
}